// Round 9
// baseline (447.314 us; speedup 1.0000x reference)
//
#include <hip/hip_runtime.h>
#include <hip/hip_bf16.h>
#include <math.h>

typedef __hip_bfloat16 bf16;
typedef _Float16 f16;
typedef __attribute__((ext_vector_type(2))) _Float16 f16x2;
typedef __attribute__((ext_vector_type(8))) short bf16x8;   // MFMA A/B frag (4 VGPRs)
typedef __attribute__((ext_vector_type(4))) float f32x4;    // MFMA C/D frag
typedef __attribute__((ext_vector_type(4))) unsigned uivec4; // native u32x4 (nontemporal-ok)

#define NT 2
#define NE 2
#define NN 50000
#define HID 128
#define NH 4
#define DD 32
#define NL 2
#define NEDGE 400000
#define MBLK64 782      // ceil(50000/64)
#define AGGB 3125       // NN/16 (16 dsts per block: 4 waves x 4 streams, 1 dst/stream)
#define WPITCH 136      // LDS row pitch (elems): 272 B, 16B-aligned, 2-way banks (free)
#define CB 196          // coarse buckets (key >> 8), covers 50176 nodes
#define CAP 4096        // bucket capacity (expected 2040, +45 sigma margin)
#define CHUNK 2048      // edges per bucket1 block
#define NCH 196         // ceil(NEDGE / CHUNK)

__device__ __forceinline__ float b2f(bf16 v) { return __bfloat162float(v); }
__device__ __forceinline__ float toF(float v) { return v; }
__device__ __forceinline__ float toF(bf16 v) { return b2f(v); }
__device__ __forceinline__ float sigm(float x) { return 1.0f / (1.0f + __expf(-x)); }
__device__ __forceinline__ unsigned short f2bits(float f) {
    bf16 h = __float2bfloat16(f);
    unsigned short b; __builtin_memcpy(&b, &h, 2); return b;
}
__device__ __forceinline__ float bits2f(unsigned short b) {
    unsigned u = ((unsigned)b) << 16; float f; __builtin_memcpy(&f, &u, 4); return f;
}
__device__ __forceinline__ unsigned short f2hbits(float f) {
    f16 h = (f16)f;
    unsigned short b; __builtin_memcpy(&b, &h, 2); return b;
}

__device__ __forceinline__ float dot8_f16(const unsigned* kr, const f16x2 q[4], float init) {
    float p = init;
#pragma unroll
    for (int i = 0; i < 4; i++) {
        f16x2 kh; __builtin_memcpy(&kh, &kr[i], 4);
#if __has_builtin(__builtin_amdgcn_fdot2)
        p = __builtin_amdgcn_fdot2(q[i], kh, p, false);
#else
        p += (float)q[i].x * (float)kh.x + (float)q[i].y * (float)kh.y;
#endif
    }
    return p;
}

// ---- input dtype detection (0 = bf16, 1 = fp32) -----------------------------
__global__ void detect_kernel(const void* __restrict__ x, int* __restrict__ flag) {
    int lane = threadIdx.x;  // 64
    const unsigned short* u = (const unsigned short*)x;
    int cnt = 0;
    for (int i = 0; i < 4; i++) {
        unsigned short w = u[lane * 4 + i];
        int e = (w >> 7) & 0xFF;
        if (e >= 110 && e <= 135) cnt++;
    }
    for (int off = 32; off > 0; off >>= 1) cnt += __shfl_xor(cnt, off, 64);
    if (lane == 0) *flag = (cnt > 200) ? 0 : 1;
}

// ---- coarse bucketing: one edge pass, dst-keyed + src-keyed -----------------
__global__ void bucket1_kernel(const int* __restrict__ ei, int* __restrict__ gcd,
                               int* __restrict__ gcs, unsigned* __restrict__ bufd,
                               unsigned* __restrict__ bufs) {
    int blk = blockIdx.x;               // NE * NCH
    int e = blk / NCH, ch = blk % NCH;
    int tid = threadIdx.x;              // 256
    __shared__ int hd[CB], hs[CB], bd[CB], bs[CB];
    for (int i = tid; i < CB; i += 256) { hd[i] = 0; hs[i] = 0; }
    __syncthreads();
    const int* srcp = ei + (e * 2 + 0) * NEDGE;
    const int* dstp = ei + (e * 2 + 1) * NEDGE;
    int j0 = ch * CHUNK;
    int src[8], dst[8], rd[8], rs[8];
#pragma unroll
    for (int i = 0; i < 8; i++) {
        int j = j0 + i * 256 + tid;
        if (j < NEDGE) {
            src[i] = srcp[j]; dst[i] = dstp[j];
            rd[i] = atomicAdd(&hd[dst[i] >> 8], 1);
            rs[i] = atomicAdd(&hs[src[i] >> 8], 1);
        } else src[i] = -1;
    }
    __syncthreads();
    for (int i = tid; i < CB; i += 256) {
        bd[i] = hd[i] ? atomicAdd(&gcd[e * CB + i], hd[i]) : 0;
        bs[i] = hs[i] ? atomicAdd(&gcs[e * CB + i], hs[i]) : 0;
    }
    __syncthreads();
#pragma unroll
    for (int i = 0; i < 8; i++) {
        int j = j0 + i * 256 + tid;
        if (j < NEDGE) {
            int bn = dst[i] >> 8;
            int pd = bd[bn] + rd[i]; if (pd >= CAP) pd = CAP - 1;   // defensive
            bufd[((size_t)e * CB + bn) * CAP + pd] =
                ((unsigned)(dst[i] & 255) << 24) | (unsigned)src[i];
            bn = src[i] >> 8;
            int ps = bs[bn] + rs[i]; if (ps >= CAP) ps = CAP - 1;   // defensive
            bufs[((size_t)e * CB + bn) * CAP + ps] =
                ((unsigned)(src[i] & 255) << 19) | (unsigned)j;
        }
    }
}

// ---- coarse-offset scan (196 bins / edge type) + offs[NN] sentinel ----------
__global__ void cscan_kernel(const int* __restrict__ gcd, int* __restrict__ coff,
                             int* __restrict__ offs) {
    int e = blockIdx.x;                 // NE
    int tid = threadIdx.x;              // 256
    __shared__ int sb[256];
    int v = (tid < CB) ? gcd[e * CB + tid] : 0;
    sb[tid] = v; __syncthreads();
    for (int off = 1; off < 256; off <<= 1) {
        int a = (tid >= off) ? sb[tid - off] : 0;
        __syncthreads();
        sb[tid] += a;
        __syncthreads();
    }
    if (tid < CB) coff[e * (CB + 1) + tid] = sb[tid] - v;   // exclusive
    if (tid == CB - 1) coff[e * (CB + 1) + CB] = sb[tid];
    if (tid == 0) offs[e * (NN + 1) + NN] = NEDGE;
}

// ---- fine pass (dst): per-bucket exact CSR offs + dst-sorted srcb -----------
__global__ void fine_dst_kernel(const unsigned* __restrict__ bufd, const int* __restrict__ gcd,
                                const int* __restrict__ coff, int* __restrict__ offs,
                                int* __restrict__ srcb) {
    int blk = blockIdx.x;               // NE * CB
    int e = blk / CB, bn = blk % CB;
    int tid = threadIdx.x;              // 256
    int cnt = gcd[e * CB + bn]; if (cnt > CAP) cnt = CAP;
    int base = coff[e * (CB + 1) + bn];
    const unsigned* b = bufd + ((size_t)e * CB + bn) * CAP;
    __shared__ int dc[256], ss[256];
    dc[tid] = 0; __syncthreads();
    for (int i = tid; i < cnt; i += 256) atomicAdd(&dc[b[i] >> 24], 1);
    __syncthreads();
    int v = dc[tid];
    ss[tid] = v; __syncthreads();
    for (int off = 1; off < 256; off <<= 1) {
        int a = (tid >= off) ? ss[tid - off] : 0;
        __syncthreads();
        ss[tid] += a;
        __syncthreads();
    }
    int excl = ss[tid] - v;
    int d = bn * 256 + tid;
    if (d < NN) offs[e * (NN + 1) + d] = base + excl;
    dc[tid] = excl;                     // reuse as scatter cursor
    __syncthreads();
    for (int i = tid; i < cnt; i += 256) {
        unsigned w = b[i];
        int r = atomicAdd(&dc[w >> 24], 1);
        srcb[(size_t)e * NEDGE + base + r] = (int)(w & 0xFFFFFF);
    }
}

// ---- fine pass (src): per-src last-edge-index max -> ewsc -------------------
__global__ void fine_src_kernel(const unsigned* __restrict__ bufs, const int* __restrict__ gcs,
                                const void* __restrict__ ew, float* __restrict__ ewsc,
                                const int* __restrict__ flag) {
    int blk = blockIdx.x;               // NE * CB
    int e = blk / CB, bn = blk % CB;
    int tid = threadIdx.x;              // 256
    int cnt = gcs[e * CB + bn]; if (cnt > CAP) cnt = CAP;
    const unsigned* b = bufs + ((size_t)e * CB + bn) * CAP;
    __shared__ int mx[256];
    mx[tid] = -1; __syncthreads();
    for (int i = tid; i < cnt; i += 256) {
        unsigned w = b[i];
        atomicMax(&mx[w >> 19], (int)(w & 0x7FFFF));
    }
    __syncthreads();
    int n = bn * 256 + tid;
    if (n < NN) {
        int mj = mx[tid];
        float v = 1.0f;
        if (mj >= 0)
            v = sigm(*flag ? ((const float*)ew)[(size_t)e * NEDGE + mj]
                           : b2f(((const bf16*)ew)[(size_t)e * NEDGE + mj]));
        ewsc[e * NN + n] = v;           // src type of edge type e == e
    }
}

// ---- weight prep: transpose + fold rel into K/V weights ---------------------
// wT layout (bf16, [n][k]): mat 0,1 = linT; mat 2+lt*3+{0,1,2} = kT_fold,qT,vT_fold
// (lt = l*2+t); mat 14+lt = aT.
template <typename T>
__device__ __forceinline__ void prep_w_body(const T* lin_w, const T* k_w, const T* q_w,
                                            const T* v_w, const T* a_w, const T* rel_att,
                                            const T* rel_msg, unsigned short* wT) {
    int bid = blockIdx.x, tid = threadIdx.x;
    int mat = bid >> 6;
    int elem = (bid & 63) * 256 + tid;
    int n = elem >> 7, k = elem & 127;
    float v;
    if (mat < 2) {
        v = toF(lin_w[(size_t)mat * 16384 + k * 128 + n]);
    } else if (mat < 14) {
        int m2 = mat - 2, lt = m2 / 3, op = m2 % 3;
        if (op == 1) {
            v = toF(q_w[(size_t)lt * 16384 + k * 128 + n]);
        } else {
            const T* w = (op == 0 ? k_w : v_w) + (size_t)lt * 16384 + k * 128;
            const T* rl = (op == 0 ? rel_att : rel_msg) + (size_t)lt * 4096;  // e == t
            int hh = n >> 5, jj = n & 31;
            float s = 0.f;
#pragma unroll 8
            for (int d = 0; d < 32; d++)
                s += toF(w[hh * 32 + d]) * toF(rl[(hh * 32 + d) * 32 + jj]);
            v = s;
        }
    } else {
        v = toF(a_w[(size_t)(mat - 14) * 16384 + k * 128 + n]);
    }
    wT[(size_t)mat * 16384 + n * 128 + k] = f2bits(v);
}
__global__ void prep_w_kernel(const void* lin_w, const void* k_w, const void* q_w,
                              const void* v_w, const void* a_w, const void* rel_att,
                              const void* rel_msg, unsigned short* wT, const int* flag) {
    if (*flag) prep_w_body<float>((const float*)lin_w, (const float*)k_w, (const float*)q_w,
                                  (const float*)v_w, (const float*)a_w, (const float*)rel_att,
                                  (const float*)rel_msg, wT);
    else       prep_w_body<bf16>((const bf16*)lin_w, (const bf16*)k_w, (const bf16*)q_w,
                                 (const bf16*)v_w, (const bf16*)a_w, (const bf16*)rel_att,
                                 (const bf16*)rel_msg, wT);
}

// ---- bias prep (fp32) + rel_p + skip ----------------------------------------
template <typename T>
__device__ __forceinline__ void prep_misc_body(const T* lin_b, const T* k_b, const T* q_b,
                                               const T* v_b, const T* a_b, const T* rel_att,
                                               const T* rel_msg, const T* rel_p, const T* skip,
                                               float* biasall, float* relpf, float* skipf) {
    int mat = blockIdx.x, n = threadIdx.x;  // 18 x 128
    float v;
    if (mat < 2) {
        v = toF(lin_b[mat * 128 + n]);
    } else if (mat < 14) {
        int m2 = mat - 2, lt = m2 / 3, op = m2 % 3;
        if (op == 1) {
            v = toF(q_b[lt * 128 + n]);
        } else {
            const T* b = (op == 0 ? k_b : v_b) + lt * 128;
            const T* rl = (op == 0 ? rel_att : rel_msg) + (size_t)lt * 4096;
            int hh = n >> 5, jj = n & 31;
            float s = 0.f;
#pragma unroll 8
            for (int d = 0; d < 32; d++)
                s += toF(b[hh * 32 + d]) * toF(rl[(hh * 32 + d) * 32 + jj]);
            v = s;
        }
    } else {
        v = toF(a_b[(mat - 14) * 128 + n]);
    }
    biasall[mat * 128 + n] = v;
    if (mat == 0 && n < 16) relpf[n] = toF(rel_p[n]);
    if (mat == 1 && n < 4) skipf[n] = toF(skip[n]);
}
__global__ void prep_misc_kernel(const void* lin_b, const void* k_b, const void* q_b,
                                 const void* v_b, const void* a_b, const void* rel_att,
                                 const void* rel_msg, const void* rel_p, const void* skip,
                                 float* biasall, float* relpf, float* skipf, const int* flag) {
    if (*flag) prep_misc_body<float>((const float*)lin_b, (const float*)k_b, (const float*)q_b,
                                     (const float*)v_b, (const float*)a_b, (const float*)rel_att,
                                     (const float*)rel_msg, (const float*)rel_p, (const float*)skip,
                                     biasall, relpf, skipf);
    else       prep_misc_body<bf16>((const bf16*)lin_b, (const bf16*)k_b, (const bf16*)q_b,
                                    (const bf16*)v_b, (const bf16*)a_b, (const bf16*)rel_att,
                                    (const bf16*)rel_msg, (const bf16*)rel_p, (const bf16*)skip,
                                    biasall, relpf, skipf);
}

// ---- shared GEMM helpers ----------------------------------------------------
__device__ __forceinline__ void stage_w(unsigned short* __restrict__ Wl,
                                        const unsigned short* __restrict__ wmat, int tid) {
#pragma unroll
    for (int i = 0; i < 8; i++) {
        int c = i * 256 + tid;           // 2048 chunks of 8
        int n = c >> 4, ko = (c & 15) * 8;
        *(bf16x8*)&Wl[n * WPITCH + ko] = *(const bf16x8*)&wmat[n * 128 + ko];
    }
}

__device__ __forceinline__ void mfma_pass(const unsigned short* __restrict__ Wl,
                                          const bf16x8 af[4], const float* __restrict__ bias,
                                          f32x4 acc[8], int m16, int quad) {
#pragma unroll
    for (int ni = 0; ni < 8; ni++) {
        float b = bias[ni * 16 + m16];
        f32x4 iv = {b, b, b, b};
        acc[ni] = iv;
    }
#pragma unroll
    for (int ks = 0; ks < 4; ks++) {
        bf16x8 a = af[ks];
#pragma unroll
        for (int ni = 0; ni < 8; ni++) {
            bf16x8 bb = *(const bf16x8*)&Wl[(ni * 16 + m16) * WPITCH + ks * 32 + quad * 8];
            acc[ni] = __builtin_amdgcn_mfma_f32_16x16x32_bf16(a, bb, acc[ni], 0, 0, 0);
        }
    }
}

// kqv 3-pass GEMM on an LDS-staged A tile (hT, bf16, C-layout transposed to
// A-layout for free by the LDS bounce). After each pass's MFMA, Wl is dead
// (restaged next pass) -- reuse it as an fp16 C-bounce tile so q/kv stores are
// 16 B/lane coalesced (256 B runs) instead of scalar 2 B (32 B segments).
__device__ __forceinline__ void kqv_passes(const unsigned short* __restrict__ hT,
                                           unsigned short* __restrict__ Wl,
                                           const unsigned short* __restrict__ wTall,
                                           const float* __restrict__ biasall, int lt,
                                           unsigned short* __restrict__ kv,
                                           unsigned short* __restrict__ qq,
                                           int t, int nb, int wave, int m16, int quad, int tid) {
    bf16x8 af2[4];
#pragma unroll
    for (int ks = 0; ks < 4; ks++)
        af2[ks] = *(const bf16x8*)&hT[(wave * 16 + m16) * WPITCH + ks * 32 + quad * 8];
    f32x4 acc[8];
#pragma unroll
    for (int pass = 0; pass < 3; pass++) {
        int mat = 2 + lt * 3 + pass;
        __syncthreads();   // prior pass's Wl reads (vec-store) done before restaging
        stage_w(Wl, wTall + (size_t)mat * 16384, tid);
        __syncthreads();
        mfma_pass(Wl, af2, biasall + mat * 128, acc, m16, quad);
        __syncthreads();   // Wl MFMA reads done -> reuse Wl as C-bounce
#pragma unroll
        for (int r = 0; r < 4; r++) {
            int rloc = wave * 16 + quad * 4 + r;
#pragma unroll
            for (int ni = 0; ni < 8; ni++)
                Wl[rloc * WPITCH + ni * 16 + m16] = f2hbits(acc[ni][r]);
        }
        __syncthreads();
        // vectorized store: 4 rounds x 256 threads x 16 B (64 rows x 256 B)
#pragma unroll
        for (int i = 0; i < 4; i++) {
            int c = i * 256 + tid;       // 1024 chunks of 8
            int row = c >> 4, ko = (c & 15) * 8;
            int node = nb + row;
            if (node < NN) {
                bf16x8 v = *(const bf16x8*)&Wl[row * WPITCH + ko];
                if (pass == 1)
                    *(bf16x8*)&qq[((size_t)t * NN + node) * 128 + ko] = v;
                else
                    *(bf16x8*)&kv[((size_t)t * NN + node) * 256 + (pass == 0 ? 0 : 128) + ko] = v;
            }
        }
    }
}

// ---- fused lin + kqv(l=0): x -> h = relu(xW+b)*ewsc -> {K|V}, q -------------
// h tile staged in LDS (bf16) so kqv's A never re-reads h from global.
// NOTE: __shared__ lives in the KERNEL (not the template body) -- otherwise the
// two template instantiations each allocate their own Wl/hT and the block's
// LDS doubles to 104 KB -> 1 block/CU (the round-7 9%-occupancy bug).
template <bool FP32>
__device__ __forceinline__ void lin_kqv_body(const void* __restrict__ x,
                                             const unsigned short* __restrict__ wTall,
                                             const float* __restrict__ biasall,
                                             const float* __restrict__ ewsc,
                                             float* __restrict__ h,
                                             unsigned short* __restrict__ kv,
                                             unsigned short* __restrict__ qq,
                                             unsigned short* __restrict__ Wl,
                                             unsigned short* __restrict__ hT) {
    int bid = blockIdx.x, tid = threadIdx.x;
    int t = bid / MBLK64, nb = (bid % MBLK64) * 64;
    int wave = tid >> 6, lane = tid & 63;
    int m16 = lane & 15, quad = lane >> 4;
    stage_w(Wl, wTall + (size_t)t * 16384, tid);
    int arow = nb + wave * 16 + m16;
    int arc = arow < NN ? arow : NN - 1;
    size_t abase = ((size_t)t * NN + arc) * 128;
    bf16x8 af[4];
#pragma unroll
    for (int ks = 0; ks < 4; ks++) {
        if (FP32) {
            const float4* s = (const float4*)((const float*)x + abase + ks * 32 + quad * 8);
            float4 f0 = s[0], f1 = s[1];
            unsigned short* pu = (unsigned short*)&af[ks];
            pu[0] = f2bits(f0.x); pu[1] = f2bits(f0.y); pu[2] = f2bits(f0.z); pu[3] = f2bits(f0.w);
            pu[4] = f2bits(f1.x); pu[5] = f2bits(f1.y); pu[6] = f2bits(f1.z); pu[7] = f2bits(f1.w);
        } else {
            af[ks] = *(const bf16x8*)((const unsigned short*)x + abase + ks * 32 + quad * 8);
        }
    }
    __syncthreads();
    f32x4 acc[8];
    mfma_pass(Wl, af, biasall + t * 128, acc, m16, quad);
#pragma unroll
    for (int r = 0; r < 4; r++) {
        int rloc = wave * 16 + quad * 4 + r;
        int node = nb + rloc;
        float es = ewsc[t * NN + (node < NN ? node : NN - 1)];
#pragma unroll
        for (int ni = 0; ni < 8; ni++) {
            float v = fmaxf(acc[ni][r], 0.f) * es;
            unsigned short vb = (node < NN) ? f2bits(v) : (unsigned short)0;
            if (node < NN) h[((size_t)t * NN + node) * 128 + ni * 16 + m16] = v;
            hT[rloc * WPITCH + ni * 16 + m16] = vb;
        }
    }
    __syncthreads();
    kqv_passes(hT, Wl, wTall, biasall, /*lt=*/t, kv, qq, t, nb, wave, m16, quad, tid);
}
__global__ void __launch_bounds__(256, 3) lin_kqv_gemm(const void* x,
                                                       const unsigned short* wTall,
                                                       const float* biasall, const float* ewsc,
                                                       float* h, unsigned short* kv,
                                                       unsigned short* qq, const int* flag) {
    __shared__ unsigned short Wl[128 * WPITCH];   // 34816 B
    __shared__ unsigned short hT[64 * WPITCH];    // 17408 B  (total 52224 -> 3 blocks/CU)
    if (*flag) lin_kqv_body<true>(x, wTall, biasall, ewsc, h, kv, qq, Wl, hT);
    else       lin_kqv_body<false>(x, wTall, biasall, ewsc, h, kv, qq, Wl, hT);
}

// ---- merged-edge-type segment-softmax aggregation (r4-proven, at line-traffic
// roofline: 512 B/edge * 800k = 410 MB L2-line traffic @ ~6.4 TB/s = ~63 us) ---
__global__ void __launch_bounds__(256) agg_kernel(const unsigned short* __restrict__ qq,
                                                  const unsigned short* __restrict__ kv,
                                                  const int* __restrict__ srcb,
                                                  const int* __restrict__ offs,
                                                  const float* __restrict__ relpf, int l,
                                                  unsigned short* __restrict__ aggb) {
    int bid = blockIdx.x;
    int e = bid / AGGB;
    int wave = threadIdx.x >> 6, lane = threadIdx.x & 63;
    int stream = lane >> 4, l4 = lane & 15;
    int dst = (bid % AGGB) * 16 + wave * 4 + stream;
    int t = 1 - e;                      // EDGE_DST=(1,0)
    int le = l * 2 + e;
    int c0 = l4 * 8, head = l4 >> 2;
    const int* offs_e = offs + e * (NN + 1);
    const int* srcb_e = srcb + (size_t)e * NEDGE;
    int beg = offs_e[dst], end = offs_e[dst + 1];
    size_t rowo = ((size_t)t * NN + dst) * 128 + c0;
    float scale = relpf[le * 4 + head] * 0.17677669529663687f * 1.44269504088896f;
    uivec4 qraw = __builtin_nontemporal_load((const uivec4*)&qq[rowo]);
    f16x2 q[4];
#pragma unroll
    for (int i = 0; i < 4; i++) { unsigned w = qraw[i]; __builtin_memcpy(&q[i], &w, 4); }
    const unsigned short* kvb = kv + (size_t)e * NN * 256;  // EDGE_SRC=(0,1): s == e
    float lsum = 0.f;
    float acc[8] = {0.f, 0.f, 0.f, 0.f, 0.f, 0.f, 0.f, 0.f};
    int jmax = end - 1;
    for (int j0 = beg; j0 < end; j0 += 4) {
        int src[4];
#pragma unroll
        for (int i = 0; i < 4; i++) {
            int j = j0 + i;
            src[i] = __builtin_nontemporal_load(&srcb_e[j <= jmax ? j : jmax]);
        }
        uivec4 kr[4], vr[4];
#pragma unroll
        for (int i = 0; i < 4; i++) {
            size_t so = (size_t)src[i] * 256 + c0;
            kr[i] = *(const uivec4*)&kvb[so];
            vr[i] = *(const uivec4*)&kvb[so + 128];
        }
#pragma unroll
        for (int i = 0; i < 4; i++) {
            float p = dot8_f16((const unsigned*)&kr[i], q, 0.f);
            p += __shfl_xor(p, 1, 64);  // reduce 4 lanes = 32 chans = one head
            p += __shfl_xor(p, 2, 64);
            float es = (j0 + i <= jmax) ? exp2f(p * scale) : 0.f;
            lsum += es;
            const unsigned* vu = (const unsigned*)&vr[i];
#pragma unroll
            for (int k = 0; k < 4; k++) {
                f16x2 vh; __builtin_memcpy(&vh, &vu[k], 4);
                acc[k * 2]     += es * (float)vh.x;
                acc[k * 2 + 1] += es * (float)vh.y;
            }
        }
    }
    float inv = 1.0f / (lsum + 1e-16f);
    unsigned short o[8];
#pragma unroll
    for (int i = 0; i < 8; i++) o[i] = f2bits(acc[i] * inv);
    *(bf16x8*)&aggb[rowo] = *(bf16x8*)o;   // all 64 lanes: 4 rows x 256B coalesced
}

// ---- fused outproj(l) + kqv(l+1): h' = beta*(gelu(agg)Wa+ba)+(1-beta)*h -----
// h' tile staged in LDS -> kqv(l+1) A-frags without global h re-read.
// aggb aliases qq: each block reads its own aggb rows before its kqv pass
// rewrites the same rows (block-private rows, barrier-ordered).
__global__ void __launch_bounds__(256, 3) outproj_kqv_gemm(const unsigned short* __restrict__ aggb,
                                                           const unsigned short* __restrict__ wTall,
                                                           const float* __restrict__ biasall,
                                                           const float* __restrict__ skipf, int l,
                                                           float* __restrict__ h,
                                                           unsigned short* __restrict__ kv,
                                                           unsigned short* __restrict__ qq) {
    __shared__ unsigned short Wl[128 * WPITCH];
    __shared__ unsigned short hT[64 * WPITCH];
    int bid = blockIdx.x, tid = threadIdx.x;
    int t = bid / MBLK64, nb = (bid % MBLK64) * 64;
    int lt = l * 2 + t;
    int wave = tid >> 6, lane = tid & 63;
    int m16 = lane & 15, quad = lane >> 4;
    int mat = 14 + lt;
    stage_w(Wl, wTall + (size_t)mat * 16384, tid);
    int arow = nb + wave * 16 + m16;
    int arc = arow < NN ? arow : NN - 1;
    size_t abase = ((size_t)t * NN + arc) * 128;
    bf16x8 af[4];
#pragma unroll
    for (int ks = 0; ks < 4; ks++) {
        bf16x8 raw = *(const bf16x8*)&aggb[abase + ks * 32 + quad * 8];
        const unsigned short* ru = (const unsigned short*)&raw;
        unsigned short* pu = (unsigned short*)&af[ks];
#pragma unroll
        for (int jj = 0; jj < 8; jj++) {
            float g = bits2f(ru[jj]);
            pu[jj] = f2bits(0.5f * g * (1.0f + erff(g * 0.70710678118654752f)));  // exact gelu
        }
    }
    __syncthreads();
    f32x4 acc[8];
    mfma_pass(Wl, af, biasall + mat * 128, acc, m16, quad);
    float beta = sigm(skipf[lt]);
#pragma unroll
    for (int r = 0; r < 4; r++) {
        int rloc = wave * 16 + quad * 4 + r;
        int node = nb + rloc;
#pragma unroll
        for (int ni = 0; ni < 8; ni++) {
            unsigned short vb = 0;
            if (node < NN) {
                size_t io = ((size_t)t * NN + node) * 128 + ni * 16 + m16;
                float nv = beta * acc[ni][r] + (1.0f - beta) * h[io];
                h[io] = nv;
                vb = f2bits(nv);
            }
            hT[rloc * WPITCH + ni * 16 + m16] = vb;
        }
    }
    __syncthreads();
    kqv_passes(hT, Wl, wTall, biasall, /*lt=*/(l + 1) * 2 + t, kv, qq, t, nb, wave, m16, quad, tid);
}

// ---- plain outproj for the last layer: writes h' and the final output -------
__global__ void __launch_bounds__(256, 4) outproj_gemm(const unsigned short* __restrict__ aggb,
                                                       const unsigned short* __restrict__ wTall,
                                                       const float* __restrict__ biasall,
                                                       const float* __restrict__ skipf, int l,
                                                       float* __restrict__ h, int last,
                                                       void* __restrict__ outp,
                                                       const int* __restrict__ flag) {
    __shared__ unsigned short Wl[128 * WPITCH];
    int bid = blockIdx.x, tid = threadIdx.x;
    int t = bid / MBLK64, nb = (bid % MBLK64) * 64;
    int lt = l * 2 + t;
    int wave = tid >> 6, lane = tid & 63;
    int m16 = lane & 15, quad = lane >> 4;
    int mat = 14 + lt;
    stage_w(Wl, wTall + (size_t)mat * 16384, tid);
    int arow = nb + wave * 16 + m16;
    int arc = arow < NN ? arow : NN - 1;
    size_t abase = ((size_t)t * NN + arc) * 128;
    bf16x8 af[4];
#pragma unroll
    for (int ks = 0; ks < 4; ks++) {
        bf16x8 raw = *(const bf16x8*)&aggb[abase + ks * 32 + quad * 8];
        const unsigned short* ru = (const unsigned short*)&raw;
        unsigned short* pu = (unsigned short*)&af[ks];
#pragma unroll
        for (int jj = 0; jj < 8; jj++) {
            float g = bits2f(ru[jj]);
            pu[jj] = f2bits(0.5f * g * (1.0f + erff(g * 0.70710678118654752f)));  // exact gelu
        }
    }
    __syncthreads();
    f32x4 acc[8];
    mfma_pass(Wl, af, biasall + mat * 128, acc, m16, quad);
    float beta = sigm(skipf[lt]);
    int fl = *flag;
#pragma unroll
    for (int r = 0; r < 4; r++) {
        int node = nb + wave * 16 + quad * 4 + r;
        if (node < NN) {
            size_t ro = ((size_t)t * NN + node) * 128;
#pragma unroll
            for (int ni = 0; ni < 8; ni++) {
                size_t io = ro + ni * 16 + m16;
                float nv = beta * acc[ni][r] + (1.0f - beta) * h[io];
                h[io] = nv;
                if (last) {
                    if (fl) ((float*)outp)[io] = nv;
                    else    ((bf16*)outp)[io] = __float2bfloat16(nv);
                }
            }
        }
    }
}

extern "C" void kernel_launch(void* const* d_in, const int* in_sizes, int n_in,
                              void* d_out, int out_size, void* d_ws, size_t ws_size,
                              hipStream_t stream) {
    const void* x      = d_in[0];
    const int*  ei     = (const int*)d_in[1];
    const void* ew     = d_in[2];
    const void* lin_w  = d_in[3];
    const void* lin_b  = d_in[4];
    const void* k_w    = d_in[5];
    const void* k_b    = d_in[6];
    const void* q_w    = d_in[7];
    const void* q_b    = d_in[8];
    const void* v_w    = d_in[9];
    const void* v_b    = d_in[10];
    const void* a_w    = d_in[11];
    const void* a_b    = d_in[12];
    const void* skip   = d_in[13];
    const void* rel_att = d_in[14];
    const void* rel_msg = d_in[15];
    const void* rel_p  = d_in[16];

    char* p = (char*)d_ws;
    auto alloc = [&](size_t bytes) -> char* {
        char* r = p;
        p += (bytes + 255) & ~(size_t)255;
        return r;
    };
    int* flag     = (int*)alloc(sizeof(int));
    int* gcd      = (int*)alloc(sizeof(int) * NE * CB);
    int* gcs      = (int*)alloc(sizeof(int) * NE * CB);
    int* coff     = (int*)alloc(sizeof(int) * NE * (CB + 1));
    int* offs     = (int*)alloc(sizeof(int) * NE * (NN + 1));
    int* srcb     = (int*)alloc(sizeof(int) * NE * NEDGE);
    unsigned* bufd = (unsigned*)alloc(sizeof(unsigned) * NE * CB * CAP);   // 6.4 MB
    unsigned* bufs = (unsigned*)alloc(sizeof(unsigned) * NE * CB * CAP);   // 6.4 MB
    unsigned short* wTall = (unsigned short*)alloc(sizeof(short) * 18 * 16384);
    float* biasall = (float*)alloc(sizeof(float) * 18 * 128);
    float* relpf   = (float*)alloc(sizeof(float) * 16);
    float* skipf   = (float*)alloc(sizeof(float) * 4);
    float* ewsc    = (float*)alloc(sizeof(float) * NT * NN);
    float* h       = (float*)alloc(sizeof(float) * NT * NN * HID);               // 51.2 MB fp32
    unsigned short* qq = (unsigned short*)alloc(sizeof(short) * NT * NN * HID);  // fp16 (aggb aliases)
    unsigned short* kv = (unsigned short*)alloc(sizeof(short) * NT * NN * HID * 2); // fp16 [K|V] interleaved
    unsigned short* aggb = qq;

    hipMemsetAsync(gcd, 0, sizeof(int) * NE * CB, stream);
    hipMemsetAsync(gcs, 0, sizeof(int) * NE * CB, stream);

    detect_kernel<<<1, 64, 0, stream>>>(x, flag);
    bucket1_kernel<<<NE * NCH, 256, 0, stream>>>(ei, gcd, gcs, bufd, bufs);
    cscan_kernel<<<NE, 256, 0, stream>>>(gcd, coff, offs);
    fine_dst_kernel<<<NE * CB, 256, 0, stream>>>(bufd, gcd, coff, offs, srcb);
    fine_src_kernel<<<NE * CB, 256, 0, stream>>>(bufs, gcs, ew, ewsc, flag);
    prep_w_kernel<<<18 * 64, 256, 0, stream>>>(lin_w, k_w, q_w, v_w, a_w, rel_att, rel_msg,
                                               wTall, flag);
    prep_misc_kernel<<<18, 128, 0, stream>>>(lin_b, k_b, q_b, v_b, a_b, rel_att, rel_msg,
                                             rel_p, skip, biasall, relpf, skipf, flag);

    // fused pipeline: lin+kqv(0) -> agg(0) -> outproj(0)+kqv(1) -> agg(1) -> outproj(1,last)
    lin_kqv_gemm<<<NT * MBLK64, 256, 0, stream>>>(x, wTall, biasall, ewsc, h, kv, qq, flag);
    agg_kernel<<<NE * AGGB, 256, 0, stream>>>(qq, kv, srcb, offs, relpf, 0, aggb);
    outproj_kqv_gemm<<<NT * MBLK64, 256, 0, stream>>>(aggb, wTall, biasall, skipf, 0, h, kv, qq);
    agg_kernel<<<NE * AGGB, 256, 0, stream>>>(qq, kv, srcb, offs, relpf, 1, aggb);
    outproj_gemm<<<NT * MBLK64, 256, 0, stream>>>(aggb, wTall, biasall, skipf, 1, h, 1,
                                                  d_out, flag);
}

// Round 11
// 423.350 us; speedup vs baseline: 1.0566x; 1.0566x over previous
//
#include <hip/hip_runtime.h>
#include <hip/hip_bf16.h>
#include <math.h>

typedef __hip_bfloat16 bf16;
typedef _Float16 f16;
typedef __attribute__((ext_vector_type(2))) _Float16 f16x2;
typedef __attribute__((ext_vector_type(8))) short bf16x8;   // MFMA A/B frag (4 VGPRs)
typedef __attribute__((ext_vector_type(4))) float f32x4;    // MFMA C/D frag
typedef __attribute__((ext_vector_type(4))) unsigned uivec4; // native u32x4 (nontemporal-ok)

#define NT 2
#define NE 2
#define NN 50000
#define HID 128
#define NH 4
#define DD 32
#define NL 2
#define NEDGE 400000
#define MBLK64 782      // ceil(50000/64)
#define AGGB 3125       // NN/16 (16 dsts per block: 4 waves x 4 streams, 1 dst/stream)
#define WPITCH 136      // LDS row pitch (elems): 272 B, 16B-aligned, bank-uniform b128
#define CB 196          // coarse buckets (key >> 8), covers 50176 nodes
#define CAP 4096        // bucket capacity (expected 2040, +45 sigma margin)
#define CHUNK 2048      // edges per bucket1 block
#define NCH 196         // ceil(NEDGE / CHUNK)

__device__ __forceinline__ float b2f(bf16 v) { return __bfloat162float(v); }
__device__ __forceinline__ float toF(float v) { return v; }
__device__ __forceinline__ float toF(bf16 v) { return b2f(v); }
__device__ __forceinline__ float sigm(float x) { return 1.0f / (1.0f + __expf(-x)); }
__device__ __forceinline__ unsigned short f2bits(float f) {
    bf16 h = __float2bfloat16(f);
    unsigned short b; __builtin_memcpy(&b, &h, 2); return b;
}
__device__ __forceinline__ float bits2f(unsigned short b) {
    unsigned u = ((unsigned)b) << 16; float f; __builtin_memcpy(&f, &u, 4); return f;
}
__device__ __forceinline__ unsigned short f2hbits(float f) {
    f16 h = (f16)f;
    unsigned short b; __builtin_memcpy(&b, &h, 2); return b;
}

__device__ __forceinline__ float dot8_f16(const unsigned* kr, const f16x2 q[4], float init) {
    float p = init;
#pragma unroll
    for (int i = 0; i < 4; i++) {
        f16x2 kh; __builtin_memcpy(&kh, &kr[i], 4);
#if __has_builtin(__builtin_amdgcn_fdot2)
        p = __builtin_amdgcn_fdot2(q[i], kh, p, false);
#else
        p += (float)q[i].x * (float)kh.x + (float)q[i].y * (float)kh.y;
#endif
    }
    return p;
}

// ---- input dtype detection (0 = bf16, 1 = fp32) + gcd/gcs zeroing -----------
__global__ void detect_kernel(const void* __restrict__ x, int* __restrict__ flag,
                              int* __restrict__ gcd, int* __restrict__ gcs) {
    int lane = threadIdx.x;  // 64
    for (int i = lane; i < NE * CB; i += 64) { gcd[i] = 0; gcs[i] = 0; }
    const unsigned short* u = (const unsigned short*)x;
    int cnt = 0;
    for (int i = 0; i < 4; i++) {
        unsigned short w = u[lane * 4 + i];
        int e = (w >> 7) & 0xFF;
        if (e >= 110 && e <= 135) cnt++;
    }
    for (int off = 32; off > 0; off >>= 1) cnt += __shfl_xor(cnt, off, 64);
    if (lane == 0) *flag = (cnt > 200) ? 0 : 1;
}

// ---- coarse bucketing: one edge pass, dst-keyed + src-keyed -----------------
__global__ void bucket1_kernel(const int* __restrict__ ei, int* __restrict__ gcd,
                               int* __restrict__ gcs, unsigned* __restrict__ bufd,
                               unsigned* __restrict__ bufs) {
    int blk = blockIdx.x;               // NE * NCH
    int e = blk / NCH, ch = blk % NCH;
    int tid = threadIdx.x;              // 256
    __shared__ int hd[CB], hs[CB], bd[CB], bs[CB];
    for (int i = tid; i < CB; i += 256) { hd[i] = 0; hs[i] = 0; }
    __syncthreads();
    const int* srcp = ei + (e * 2 + 0) * NEDGE;
    const int* dstp = ei + (e * 2 + 1) * NEDGE;
    int j0 = ch * CHUNK;
    int src[8], dst[8], rd[8], rs[8];
#pragma unroll
    for (int i = 0; i < 8; i++) {
        int j = j0 + i * 256 + tid;
        if (j < NEDGE) {
            src[i] = srcp[j]; dst[i] = dstp[j];
            rd[i] = atomicAdd(&hd[dst[i] >> 8], 1);
            rs[i] = atomicAdd(&hs[src[i] >> 8], 1);
        } else src[i] = -1;
    }
    __syncthreads();
    for (int i = tid; i < CB; i += 256) {
        bd[i] = hd[i] ? atomicAdd(&gcd[e * CB + i], hd[i]) : 0;
        bs[i] = hs[i] ? atomicAdd(&gcs[e * CB + i], hs[i]) : 0;
    }
    __syncthreads();
#pragma unroll
    for (int i = 0; i < 8; i++) {
        int j = j0 + i * 256 + tid;
        if (j < NEDGE) {
            int bn = dst[i] >> 8;
            int pd = bd[bn] + rd[i]; if (pd >= CAP) pd = CAP - 1;   // defensive
            bufd[((size_t)e * CB + bn) * CAP + pd] =
                ((unsigned)(dst[i] & 255) << 24) | (unsigned)src[i];
            bn = src[i] >> 8;
            int ps = bs[bn] + rs[i]; if (ps >= CAP) ps = CAP - 1;   // defensive
            bufs[((size_t)e * CB + bn) * CAP + ps] =
                ((unsigned)(src[i] & 255) << 19) | (unsigned)j;
        }
    }
}

// ---- coarse-offset scan (196 bins / edge type) + offs[NN] sentinel ----------
__global__ void cscan_kernel(const int* __restrict__ gcd, int* __restrict__ coff,
                             int* __restrict__ offs) {
    int e = blockIdx.x;                 // NE
    int tid = threadIdx.x;              // 256
    __shared__ int sb[256];
    int v = (tid < CB) ? gcd[e * CB + tid] : 0;
    sb[tid] = v; __syncthreads();
    for (int off = 1; off < 256; off <<= 1) {
        int a = (tid >= off) ? sb[tid - off] : 0;
        __syncthreads();
        sb[tid] += a;
        __syncthreads();
    }
    if (tid < CB) coff[e * (CB + 1) + tid] = sb[tid] - v;   // exclusive
    if (tid == CB - 1) coff[e * (CB + 1) + CB] = sb[tid];
    if (tid == 0) offs[e * (NN + 1) + NN] = NEDGE;
}

// ---- fine pass (dst): per-bucket exact CSR offs + dst-sorted srcb -----------
__global__ void fine_dst_kernel(const unsigned* __restrict__ bufd, const int* __restrict__ gcd,
                                const int* __restrict__ coff, int* __restrict__ offs,
                                int* __restrict__ srcb) {
    int blk = blockIdx.x;               // NE * CB
    int e = blk / CB, bn = blk % CB;
    int tid = threadIdx.x;              // 256
    int cnt = gcd[e * CB + bn]; if (cnt > CAP) cnt = CAP;
    int base = coff[e * (CB + 1) + bn];
    const unsigned* b = bufd + ((size_t)e * CB + bn) * CAP;
    __shared__ int dc[256], ss[256];
    dc[tid] = 0; __syncthreads();
    for (int i = tid; i < cnt; i += 256) atomicAdd(&dc[b[i] >> 24], 1);
    __syncthreads();
    int v = dc[tid];
    ss[tid] = v; __syncthreads();
    for (int off = 1; off < 256; off <<= 1) {
        int a = (tid >= off) ? ss[tid - off] : 0;
        __syncthreads();
        ss[tid] += a;
        __syncthreads();
    }
    int excl = ss[tid] - v;
    int d = bn * 256 + tid;
    if (d < NN) offs[e * (NN + 1) + d] = base + excl;
    dc[tid] = excl;                     // reuse as scatter cursor
    __syncthreads();
    for (int i = tid; i < cnt; i += 256) {
        unsigned w = b[i];
        int r = atomicAdd(&dc[w >> 24], 1);
        srcb[(size_t)e * NEDGE + base + r] = (int)(w & 0xFFFFFF);
    }
}

// ---- fine pass (src): per-src last-edge-index max -> ewsc -------------------
__global__ void fine_src_kernel(const unsigned* __restrict__ bufs, const int* __restrict__ gcs,
                                const void* __restrict__ ew, float* __restrict__ ewsc,
                                const int* __restrict__ flag) {
    int blk = blockIdx.x;               // NE * CB
    int e = blk / CB, bn = blk % CB;
    int tid = threadIdx.x;              // 256
    int cnt = gcs[e * CB + bn]; if (cnt > CAP) cnt = CAP;
    const unsigned* b = bufs + ((size_t)e * CB + bn) * CAP;
    __shared__ int mx[256];
    mx[tid] = -1; __syncthreads();
    for (int i = tid; i < cnt; i += 256) {
        unsigned w = b[i];
        atomicMax(&mx[w >> 19], (int)(w & 0x7FFFF));
    }
    __syncthreads();
    int n = bn * 256 + tid;
    if (n < NN) {
        int mj = mx[tid];
        float v = 1.0f;
        if (mj >= 0)
            v = sigm(*flag ? ((const float*)ew)[(size_t)e * NEDGE + mj]
                           : b2f(((const bf16*)ew)[(size_t)e * NEDGE + mj]));
        ewsc[e * NN + n] = v;           // src type of edge type e == e
    }
}

// ---- weight prep: transpose + fold rel into K/V weights ---------------------
// wT layout (bf16, [n][k]): mat 0,1 = linT; mat 2+lt*3+{0,1,2} = kT_fold,qT,vT_fold
// (lt = l*2+t); mat 14+lt = aT.
template <typename T>
__device__ __forceinline__ void prep_w_body(const T* lin_w, const T* k_w, const T* q_w,
                                            const T* v_w, const T* a_w, const T* rel_att,
                                            const T* rel_msg, unsigned short* wT) {
    int bid = blockIdx.x, tid = threadIdx.x;
    int mat = bid >> 6;
    int elem = (bid & 63) * 256 + tid;
    int n = elem >> 7, k = elem & 127;
    float v;
    if (mat < 2) {
        v = toF(lin_w[(size_t)mat * 16384 + k * 128 + n]);
    } else if (mat < 14) {
        int m2 = mat - 2, lt = m2 / 3, op = m2 % 3;
        if (op == 1) {
            v = toF(q_w[(size_t)lt * 16384 + k * 128 + n]);
        } else {
            const T* w = (op == 0 ? k_w : v_w) + (size_t)lt * 16384 + k * 128;
            const T* rl = (op == 0 ? rel_att : rel_msg) + (size_t)lt * 4096;  // e == t
            int hh = n >> 5, jj = n & 31;
            float s = 0.f;
#pragma unroll 8
            for (int d = 0; d < 32; d++)
                s += toF(w[hh * 32 + d]) * toF(rl[(hh * 32 + d) * 32 + jj]);
            v = s;
        }
    } else {
        v = toF(a_w[(size_t)(mat - 14) * 16384 + k * 128 + n]);
    }
    wT[(size_t)mat * 16384 + n * 128 + k] = f2bits(v);
}
__global__ void prep_w_kernel(const void* lin_w, const void* k_w, const void* q_w,
                              const void* v_w, const void* a_w, const void* rel_att,
                              const void* rel_msg, unsigned short* wT, const int* flag) {
    if (*flag) prep_w_body<float>((const float*)lin_w, (const float*)k_w, (const float*)q_w,
                                  (const float*)v_w, (const float*)a_w, (const float*)rel_att,
                                  (const float*)rel_msg, wT);
    else       prep_w_body<bf16>((const bf16*)lin_w, (const bf16*)k_w, (const bf16*)q_w,
                                 (const bf16*)v_w, (const bf16*)a_w, (const bf16*)rel_att,
                                 (const bf16*)rel_msg, wT);
}

// ---- bias prep (fp32) + rel_p + skip ----------------------------------------
template <typename T>
__device__ __forceinline__ void prep_misc_body(const T* lin_b, const T* k_b, const T* q_b,
                                               const T* v_b, const T* a_b, const T* rel_att,
                                               const T* rel_msg, const T* rel_p, const T* skip,
                                               float* biasall, float* relpf, float* skipf) {
    int mat = blockIdx.x, n = threadIdx.x;  // 18 x 128
    float v;
    if (mat < 2) {
        v = toF(lin_b[mat * 128 + n]);
    } else if (mat < 14) {
        int m2 = mat - 2, lt = m2 / 3, op = m2 % 3;
        if (op == 1) {
            v = toF(q_b[lt * 128 + n]);
        } else {
            const T* b = (op == 0 ? k_b : v_b) + lt * 128;
            const T* rl = (op == 0 ? rel_att : rel_msg) + (size_t)lt * 4096;
            int hh = n >> 5, jj = n & 31;
            float s = 0.f;
#pragma unroll 8
            for (int d = 0; d < 32; d++)
                s += toF(b[hh * 32 + d]) * toF(rl[(hh * 32 + d) * 32 + jj]);
            v = s;
        }
    } else {
        v = toF(a_b[(mat - 14) * 128 + n]);
    }
    biasall[mat * 128 + n] = v;
    if (mat == 0 && n < 16) relpf[n] = toF(rel_p[n]);
    if (mat == 1 && n < 4) skipf[n] = toF(skip[n]);
}
__global__ void prep_misc_kernel(const void* lin_b, const void* k_b, const void* q_b,
                                 const void* v_b, const void* a_b, const void* rel_att,
                                 const void* rel_msg, const void* rel_p, const void* skip,
                                 float* biasall, float* relpf, float* skipf, const int* flag) {
    if (*flag) prep_misc_body<float>((const float*)lin_b, (const float*)k_b, (const float*)q_b,
                                     (const float*)v_b, (const float*)a_b, (const float*)rel_att,
                                     (const float*)rel_msg, (const float*)rel_p, (const float*)skip,
                                     biasall, relpf, skipf);
    else       prep_misc_body<bf16>((const bf16*)lin_b, (const bf16*)k_b, (const bf16*)q_b,
                                    (const bf16*)v_b, (const bf16*)a_b, (const bf16*)rel_att,
                                    (const bf16*)rel_msg, (const bf16*)rel_p, (const bf16*)skip,
                                    biasall, relpf, skipf);
}

// ---- shared GEMM helpers ----------------------------------------------------
__device__ __forceinline__ void stage_w(unsigned short* __restrict__ Wl,
                                        const unsigned short* __restrict__ wmat, int tid) {
#pragma unroll
    for (int i = 0; i < 8; i++) {
        int c = i * 256 + tid;           // 2048 chunks of 8
        int n = c >> 4, ko = (c & 15) * 8;
        *(bf16x8*)&Wl[n * WPITCH + ko] = *(const bf16x8*)&wmat[n * 128 + ko];
    }
}

__device__ __forceinline__ void mfma_pass(const unsigned short* __restrict__ Wl,
                                          const bf16x8 af[4], const float* __restrict__ bias,
                                          f32x4 acc[8], int m16, int quad) {
#pragma unroll
    for (int ni = 0; ni < 8; ni++) {
        float b = bias[ni * 16 + m16];
        f32x4 iv = {b, b, b, b};
        acc[ni] = iv;
    }
#pragma unroll
    for (int ks = 0; ks < 4; ks++) {
        bf16x8 a = af[ks];
#pragma unroll
        for (int ni = 0; ni < 8; ni++) {
            bf16x8 bb = *(const bf16x8*)&Wl[(ni * 16 + m16) * WPITCH + ks * 32 + quad * 8];
            acc[ni] = __builtin_amdgcn_mfma_f32_16x16x32_bf16(a, bb, acc[ni], 0, 0, 0);
        }
    }
}

// kqv 3-pass GEMM on an LDS-staged A tile (hT, bf16, C-layout transposed to
// A-layout for free by the LDS bounce). Writes K/V interleaved + q.
// (Scalar 2B q/kv stores are fine: L2 write-combining merges them -- measured
// WRITE_SIZE identical to a vectorized LDS-bounce variant, which regressed
// from the extra barrier/store-drain serialization. Round-9 lesson.)
__device__ __forceinline__ void kqv_passes(const unsigned short* __restrict__ hT,
                                           unsigned short* __restrict__ Wl,
                                           const unsigned short* __restrict__ wTall,
                                           const float* __restrict__ biasall, int lt,
                                           unsigned short* __restrict__ kv,
                                           unsigned short* __restrict__ qq,
                                           int t, int nb, int wave, int m16, int quad, int tid) {
    bf16x8 af2[4];
#pragma unroll
    for (int ks = 0; ks < 4; ks++)
        af2[ks] = *(const bf16x8*)&hT[(wave * 16 + m16) * WPITCH + ks * 32 + quad * 8];
    f32x4 acc[8];
#pragma unroll
    for (int pass = 0; pass < 3; pass++) {
        int mat = 2 + lt * 3 + pass;
        __syncthreads();   // prior pass's MFMA reads done before restaging W
        stage_w(Wl, wTall + (size_t)mat * 16384, tid);
        __syncthreads();
        mfma_pass(Wl, af2, biasall + mat * 128, acc, m16, quad);
#pragma unroll
        for (int r = 0; r < 4; r++) {
            int node = nb + wave * 16 + quad * 4 + r;
            if (node < NN) {
#pragma unroll
                for (int ni = 0; ni < 8; ni++) {
                    unsigned short hb = f2hbits(acc[ni][r]);
                    int c = ni * 16 + m16;
                    if (pass == 1) {
                        qq[((size_t)t * NN + node) * 128 + c] = hb;
                    } else {
                        size_t ro = ((size_t)t * NN + node) * 256 + (pass == 0 ? 0 : 128);
                        kv[ro + c] = hb;
                    }
                }
            }
        }
    }
}

// ---- fused lin + kqv(l=0): x -> h = relu(xW+b)*ewsc -> {K|V}, q -------------
// h tile staged in LDS (bf16) so kqv's A never re-reads h from global.
// NOTE: __shared__ lives in the KERNEL (not the template body) -- otherwise the
// two template instantiations each allocate their own Wl/hT and the block's
// LDS doubles to 104 KB -> 1 block/CU (the round-7 9%-occupancy bug).
template <bool FP32>
__device__ __forceinline__ void lin_kqv_body(const void* __restrict__ x,
                                             const unsigned short* __restrict__ wTall,
                                             const float* __restrict__ biasall,
                                             const float* __restrict__ ewsc,
                                             float* __restrict__ h,
                                             unsigned short* __restrict__ kv,
                                             unsigned short* __restrict__ qq,
                                             unsigned short* __restrict__ Wl,
                                             unsigned short* __restrict__ hT) {
    int bid = blockIdx.x, tid = threadIdx.x;
    int t = bid / MBLK64, nb = (bid % MBLK64) * 64;
    int wave = tid >> 6, lane = tid & 63;
    int m16 = lane & 15, quad = lane >> 4;
    stage_w(Wl, wTall + (size_t)t * 16384, tid);
    int arow = nb + wave * 16 + m16;
    int arc = arow < NN ? arow : NN - 1;
    size_t abase = ((size_t)t * NN + arc) * 128;
    bf16x8 af[4];
#pragma unroll
    for (int ks = 0; ks < 4; ks++) {
        if (FP32) {
            const float4* s = (const float4*)((const float*)x + abase + ks * 32 + quad * 8);
            float4 f0 = s[0], f1 = s[1];
            unsigned short* pu = (unsigned short*)&af[ks];
            pu[0] = f2bits(f0.x); pu[1] = f2bits(f0.y); pu[2] = f2bits(f0.z); pu[3] = f2bits(f0.w);
            pu[4] = f2bits(f1.x); pu[5] = f2bits(f1.y); pu[6] = f2bits(f1.z); pu[7] = f2bits(f1.w);
        } else {
            af[ks] = *(const bf16x8*)((const unsigned short*)x + abase + ks * 32 + quad * 8);
        }
    }
    __syncthreads();
    f32x4 acc[8];
    mfma_pass(Wl, af, biasall + t * 128, acc, m16, quad);
#pragma unroll
    for (int r = 0; r < 4; r++) {
        int rloc = wave * 16 + quad * 4 + r;
        int node = nb + rloc;
        float es = ewsc[t * NN + (node < NN ? node : NN - 1)];
#pragma unroll
        for (int ni = 0; ni < 8; ni++) {
            float v = fmaxf(acc[ni][r], 0.f) * es;
            unsigned short vb = (node < NN) ? f2bits(v) : (unsigned short)0;
            if (node < NN) h[((size_t)t * NN + node) * 128 + ni * 16 + m16] = v;
            hT[rloc * WPITCH + ni * 16 + m16] = vb;
        }
    }
    __syncthreads();
    kqv_passes(hT, Wl, wTall, biasall, /*lt=*/t, kv, qq, t, nb, wave, m16, quad, tid);
}
__global__ void __launch_bounds__(256, 3) lin_kqv_gemm(const void* x,
                                                       const unsigned short* wTall,
                                                       const float* biasall, const float* ewsc,
                                                       float* h, unsigned short* kv,
                                                       unsigned short* qq, const int* flag) {
    __shared__ unsigned short Wl[128 * WPITCH];   // 34816 B
    __shared__ unsigned short hT[64 * WPITCH];    // 17408 B  (total 52224 -> 3 blocks/CU)
    if (*flag) lin_kqv_body<true>(x, wTall, biasall, ewsc, h, kv, qq, Wl, hT);
    else       lin_kqv_body<false>(x, wTall, biasall, ewsc, h, kv, qq, Wl, hT);
}

// ---- merged-edge-type segment-softmax aggregation (r4-proven, at line-traffic
// roofline: 512 B/edge * 800k = 410 MB L2-line traffic @ ~6.4 TB/s = ~63 us) ---
__global__ void __launch_bounds__(256) agg_kernel(const unsigned short* __restrict__ qq,
                                                  const unsigned short* __restrict__ kv,
                                                  const int* __restrict__ srcb,
                                                  const int* __restrict__ offs,
                                                  const float* __restrict__ relpf, int l,
                                                  unsigned short* __restrict__ aggb) {
    int bid = blockIdx.x;
    int e = bid / AGGB;
    int wave = threadIdx.x >> 6, lane = threadIdx.x & 63;
    int stream = lane >> 4, l4 = lane & 15;
    int dst = (bid % AGGB) * 16 + wave * 4 + stream;
    int t = 1 - e;                      // EDGE_DST=(1,0)
    int le = l * 2 + e;
    int c0 = l4 * 8, head = l4 >> 2;
    const int* offs_e = offs + e * (NN + 1);
    const int* srcb_e = srcb + (size_t)e * NEDGE;
    int beg = offs_e[dst], end = offs_e[dst + 1];
    size_t rowo = ((size_t)t * NN + dst) * 128 + c0;
    float scale = relpf[le * 4 + head] * 0.17677669529663687f * 1.44269504088896f;
    uivec4 qraw = __builtin_nontemporal_load((const uivec4*)&qq[rowo]);
    f16x2 q[4];
#pragma unroll
    for (int i = 0; i < 4; i++) { unsigned w = qraw[i]; __builtin_memcpy(&q[i], &w, 4); }
    const unsigned short* kvb = kv + (size_t)e * NN * 256;  // EDGE_SRC=(0,1): s == e
    float lsum = 0.f;
    float acc[8] = {0.f, 0.f, 0.f, 0.f, 0.f, 0.f, 0.f, 0.f};
    int jmax = end - 1;
    for (int j0 = beg; j0 < end; j0 += 4) {
        int src[4];
#pragma unroll
        for (int i = 0; i < 4; i++) {
            int j = j0 + i;
            src[i] = __builtin_nontemporal_load(&srcb_e[j <= jmax ? j : jmax]);
        }
        uivec4 kr[4], vr[4];
#pragma unroll
        for (int i = 0; i < 4; i++) {
            size_t so = (size_t)src[i] * 256 + c0;
            kr[i] = *(const uivec4*)&kvb[so];
            vr[i] = *(const uivec4*)&kvb[so + 128];
        }
#pragma unroll
        for (int i = 0; i < 4; i++) {
            float p = dot8_f16((const unsigned*)&kr[i], q, 0.f);
            p += __shfl_xor(p, 1, 64);  // reduce 4 lanes = 32 chans = one head
            p += __shfl_xor(p, 2, 64);
            float es = (j0 + i <= jmax) ? exp2f(p * scale) : 0.f;
            lsum += es;
            const unsigned* vu = (const unsigned*)&vr[i];
#pragma unroll
            for (int k = 0; k < 4; k++) {
                f16x2 vh; __builtin_memcpy(&vh, &vu[k], 4);
                acc[k * 2]     += es * (float)vh.x;
                acc[k * 2 + 1] += es * (float)vh.y;
            }
        }
    }
    float inv = 1.0f / (lsum + 1e-16f);
    unsigned short o[8];
#pragma unroll
    for (int i = 0; i < 8; i++) o[i] = f2bits(acc[i] * inv);
    *(bf16x8*)&aggb[rowo] = *(bf16x8*)o;   // all 64 lanes: 4 rows x 256B coalesced
}

// ---- fused outproj(l) + kqv(l+1): h' = beta*(gelu(agg)Wa+ba)+(1-beta)*h -----
// h' tile staged in LDS -> kqv(l+1) A-frags without global h re-read.
// aggb aliases qq: each block reads its own aggb rows before its kqv pass
// rewrites the same rows (block-private rows, barrier-ordered).
__global__ void __launch_bounds__(256, 3) outproj_kqv_gemm(const unsigned short* __restrict__ aggb,
                                                           const unsigned short* __restrict__ wTall,
                                                           const float* __restrict__ biasall,
                                                           const float* __restrict__ skipf, int l,
                                                           float* __restrict__ h,
                                                           unsigned short* __restrict__ kv,
                                                           unsigned short* __restrict__ qq) {
    __shared__ unsigned short Wl[128 * WPITCH];
    __shared__ unsigned short hT[64 * WPITCH];
    int bid = blockIdx.x, tid = threadIdx.x;
    int t = bid / MBLK64, nb = (bid % MBLK64) * 64;
    int lt = l * 2 + t;
    int wave = tid >> 6, lane = tid & 63;
    int m16 = lane & 15, quad = lane >> 4;
    int mat = 14 + lt;
    stage_w(Wl, wTall + (size_t)mat * 16384, tid);
    int arow = nb + wave * 16 + m16;
    int arc = arow < NN ? arow : NN - 1;
    size_t abase = ((size_t)t * NN + arc) * 128;
    bf16x8 af[4];
#pragma unroll
    for (int ks = 0; ks < 4; ks++) {
        bf16x8 raw = *(const bf16x8*)&aggb[abase + ks * 32 + quad * 8];
        const unsigned short* ru = (const unsigned short*)&raw;
        unsigned short* pu = (unsigned short*)&af[ks];
#pragma unroll
        for (int jj = 0; jj < 8; jj++) {
            float g = bits2f(ru[jj]);
            pu[jj] = f2bits(0.5f * g * (1.0f + erff(g * 0.70710678118654752f)));  // exact gelu
        }
    }
    __syncthreads();
    f32x4 acc[8];
    mfma_pass(Wl, af, biasall + mat * 128, acc, m16, quad);
    float beta = sigm(skipf[lt]);
#pragma unroll
    for (int r = 0; r < 4; r++) {
        int rloc = wave * 16 + quad * 4 + r;
        int node = nb + rloc;
#pragma unroll
        for (int ni = 0; ni < 8; ni++) {
            unsigned short vb = 0;
            if (node < NN) {
                size_t io = ((size_t)t * NN + node) * 128 + ni * 16 + m16;
                float nv = beta * acc[ni][r] + (1.0f - beta) * h[io];
                h[io] = nv;
                vb = f2bits(nv);
            }
            hT[rloc * WPITCH + ni * 16 + m16] = vb;
        }
    }
    __syncthreads();
    kqv_passes(hT, Wl, wTall, biasall, /*lt=*/(l + 1) * 2 + t, kv, qq, t, nb, wave, m16, quad, tid);
}

// ---- plain outproj for the last layer: writes h' and the final output -------
__global__ void __launch_bounds__(256, 4) outproj_gemm(const unsigned short* __restrict__ aggb,
                                                       const unsigned short* __restrict__ wTall,
                                                       const float* __restrict__ biasall,
                                                       const float* __restrict__ skipf, int l,
                                                       float* __restrict__ h, int last,
                                                       void* __restrict__ outp,
                                                       const int* __restrict__ flag) {
    __shared__ unsigned short Wl[128 * WPITCH];
    int bid = blockIdx.x, tid = threadIdx.x;
    int t = bid / MBLK64, nb = (bid % MBLK64) * 64;
    int lt = l * 2 + t;
    int wave = tid >> 6, lane = tid & 63;
    int m16 = lane & 15, quad = lane >> 4;
    int mat = 14 + lt;
    stage_w(Wl, wTall + (size_t)mat * 16384, tid);
    int arow = nb + wave * 16 + m16;
    int arc = arow < NN ? arow : NN - 1;
    size_t abase = ((size_t)t * NN + arc) * 128;
    bf16x8 af[4];
#pragma unroll
    for (int ks = 0; ks < 4; ks++) {
        bf16x8 raw = *(const bf16x8*)&aggb[abase + ks * 32 + quad * 8];
        const unsigned short* ru = (const unsigned short*)&raw;
        unsigned short* pu = (unsigned short*)&af[ks];
#pragma unroll
        for (int jj = 0; jj < 8; jj++) {
            float g = bits2f(ru[jj]);
            pu[jj] = f2bits(0.5f * g * (1.0f + erff(g * 0.70710678118654752f)));  // exact gelu
        }
    }
    __syncthreads();
    f32x4 acc[8];
    mfma_pass(Wl, af, biasall + mat * 128, acc, m16, quad);
    float beta = sigm(skipf[lt]);
    int fl = *flag;
#pragma unroll
    for (int r = 0; r < 4; r++) {
        int node = nb + wave * 16 + quad * 4 + r;
        if (node < NN) {
            size_t ro = ((size_t)t * NN + node) * 128;
#pragma unroll
            for (int ni = 0; ni < 8; ni++) {
                size_t io = ro + ni * 16 + m16;
                float nv = beta * acc[ni][r] + (1.0f - beta) * h[io];
                h[io] = nv;
                if (last) {
                    if (fl) ((float*)outp)[io] = nv;
                    else    ((bf16*)outp)[io] = __float2bfloat16(nv);
                }
            }
        }
    }
}

extern "C" void kernel_launch(void* const* d_in, const int* in_sizes, int n_in,
                              void* d_out, int out_size, void* d_ws, size_t ws_size,
                              hipStream_t stream) {
    const void* x      = d_in[0];
    const int*  ei     = (const int*)d_in[1];
    const void* ew     = d_in[2];
    const void* lin_w  = d_in[3];
    const void* lin_b  = d_in[4];
    const void* k_w    = d_in[5];
    const void* k_b    = d_in[6];
    const void* q_w    = d_in[7];
    const void* q_b    = d_in[8];
    const void* v_w    = d_in[9];
    const void* v_b    = d_in[10];
    const void* a_w    = d_in[11];
    const void* a_b    = d_in[12];
    const void* skip   = d_in[13];
    const void* rel_att = d_in[14];
    const void* rel_msg = d_in[15];
    const void* rel_p  = d_in[16];

    char* p = (char*)d_ws;
    auto alloc = [&](size_t bytes) -> char* {
        char* r = p;
        p += (bytes + 255) & ~(size_t)255;
        return r;
    };
    int* flag     = (int*)alloc(sizeof(int));
    int* gcd      = (int*)alloc(sizeof(int) * NE * CB);
    int* gcs      = (int*)alloc(sizeof(int) * NE * CB);
    int* coff     = (int*)alloc(sizeof(int) * NE * (CB + 1));
    int* offs     = (int*)alloc(sizeof(int) * NE * (NN + 1));
    int* srcb     = (int*)alloc(sizeof(int) * NE * NEDGE);
    unsigned* bufd = (unsigned*)alloc(sizeof(unsigned) * NE * CB * CAP);   // 6.4 MB
    unsigned* bufs = (unsigned*)alloc(sizeof(unsigned) * NE * CB * CAP);   // 6.4 MB
    unsigned short* wTall = (unsigned short*)alloc(sizeof(short) * 18 * 16384);
    float* biasall = (float*)alloc(sizeof(float) * 18 * 128);
    float* relpf   = (float*)alloc(sizeof(float) * 16);
    float* skipf   = (float*)alloc(sizeof(float) * 4);
    float* ewsc    = (float*)alloc(sizeof(float) * NT * NN);
    float* h       = (float*)alloc(sizeof(float) * NT * NN * HID);               // 51.2 MB fp32
    unsigned short* qq = (unsigned short*)alloc(sizeof(short) * NT * NN * HID);  // fp16 (aggb aliases)
    unsigned short* kv = (unsigned short*)alloc(sizeof(short) * NT * NN * HID * 2); // fp16 [K|V] interleaved
    unsigned short* aggb = qq;

    detect_kernel<<<1, 64, 0, stream>>>(x, flag, gcd, gcs);
    bucket1_kernel<<<NE * NCH, 256, 0, stream>>>(ei, gcd, gcs, bufd, bufs);
    cscan_kernel<<<NE, 256, 0, stream>>>(gcd, coff, offs);
    fine_dst_kernel<<<NE * CB, 256, 0, stream>>>(bufd, gcd, coff, offs, srcb);
    fine_src_kernel<<<NE * CB, 256, 0, stream>>>(bufs, gcs, ew, ewsc, flag);
    prep_w_kernel<<<18 * 64, 256, 0, stream>>>(lin_w, k_w, q_w, v_w, a_w, rel_att, rel_msg,
                                               wTall, flag);
    prep_misc_kernel<<<18, 128, 0, stream>>>(lin_b, k_b, q_b, v_b, a_b, rel_att, rel_msg,
                                             rel_p, skip, biasall, relpf, skipf, flag);

    // fused pipeline: lin+kqv(0) -> agg(0) -> outproj(0)+kqv(1) -> agg(1) -> outproj(1,last)
    lin_kqv_gemm<<<NT * MBLK64, 256, 0, stream>>>(x, wTall, biasall, ewsc, h, kv, qq, flag);
    agg_kernel<<<NE * AGGB, 256, 0, stream>>>(qq, kv, srcb, offs, relpf, 0, aggb);
    outproj_kqv_gemm<<<NT * MBLK64, 256, 0, stream>>>(aggb, wTall, biasall, skipf, 0, h, kv, qq);
    agg_kernel<<<NE * AGGB, 256, 0, stream>>>(qq, kv, srcb, offs, relpf, 1, aggb);
    outproj_gemm<<<NT * MBLK64, 256, 0, stream>>>(aggb, wTall, biasall, skipf, 1, h, 1,
                                                  d_out, flag);
}

// Round 12
// 416.998 us; speedup vs baseline: 1.0727x; 1.0152x over previous
//
#include <hip/hip_runtime.h>
#include <hip/hip_bf16.h>
#include <math.h>

typedef __hip_bfloat16 bf16;
typedef _Float16 f16;
typedef __attribute__((ext_vector_type(2))) _Float16 f16x2;
typedef __attribute__((ext_vector_type(8))) short bf16x8;   // MFMA A/B frag (4 VGPRs)
typedef __attribute__((ext_vector_type(4))) float f32x4;    // MFMA C/D frag
typedef __attribute__((ext_vector_type(4))) unsigned uivec4; // native u32x4 (nontemporal-ok)

#define NT 2
#define NE 2
#define NN 50000
#define HID 128
#define NH 4
#define DD 32
#define NL 2
#define NEDGE 400000
#define MBLK64 782      // ceil(50000/64)
#define AGGB 3125       // NN/16 (16 dsts per block: 4 waves x 4 streams, 1 dst/stream)
#define WPITCH 136      // LDS row pitch (elems): 272 B, 16B-aligned, bank-uniform b128
#define CB 196          // coarse buckets (key >> 8), covers 50176 nodes
#define CAP 4096        // bucket capacity (expected 2040, +45 sigma margin)
#define CHUNK 2048      // edges per bucket1 block
#define NCH 196         // ceil(NEDGE / CHUNK)

__device__ __forceinline__ float b2f(bf16 v) { return __bfloat162float(v); }
__device__ __forceinline__ float toF(float v) { return v; }
__device__ __forceinline__ float toF(bf16 v) { return b2f(v); }
__device__ __forceinline__ float sigm(float x) { return 1.0f / (1.0f + __expf(-x)); }
__device__ __forceinline__ unsigned short f2bits(float f) {
    bf16 h = __float2bfloat16(f);
    unsigned short b; __builtin_memcpy(&b, &h, 2); return b;
}
__device__ __forceinline__ float bits2f(unsigned short b) {
    unsigned u = ((unsigned)b) << 16; float f; __builtin_memcpy(&f, &u, 4); return f;
}
__device__ __forceinline__ unsigned short f2hbits(float f) {
    f16 h = (f16)f;
    unsigned short b; __builtin_memcpy(&b, &h, 2); return b;
}

__device__ __forceinline__ float dot8_f16(const unsigned* kr, const f16x2 q[4], float init) {
    float p = init;
#pragma unroll
    for (int i = 0; i < 4; i++) {
        f16x2 kh; __builtin_memcpy(&kh, &kr[i], 4);
#if __has_builtin(__builtin_amdgcn_fdot2)
        p = __builtin_amdgcn_fdot2(q[i], kh, p, false);
#else
        p += (float)q[i].x * (float)kh.x + (float)q[i].y * (float)kh.y;
#endif
    }
    return p;
}

// ---- input dtype detection (0 = bf16, 1 = fp32) + gcd/gcs zeroing -----------
__global__ void detect_kernel(const void* __restrict__ x, int* __restrict__ flag,
                              int* __restrict__ gcd, int* __restrict__ gcs) {
    int lane = threadIdx.x;  // 64
    for (int i = lane; i < NE * CB; i += 64) { gcd[i] = 0; gcs[i] = 0; }
    const unsigned short* u = (const unsigned short*)x;
    int cnt = 0;
    for (int i = 0; i < 4; i++) {
        unsigned short w = u[lane * 4 + i];
        int e = (w >> 7) & 0xFF;
        if (e >= 110 && e <= 135) cnt++;
    }
    for (int off = 32; off > 0; off >>= 1) cnt += __shfl_xor(cnt, off, 64);
    if (lane == 0) *flag = (cnt > 200) ? 0 : 1;
}

// ---- coarse bucketing: one edge pass, dst-keyed + src-keyed -----------------
__global__ void bucket1_kernel(const int* __restrict__ ei, int* __restrict__ gcd,
                               int* __restrict__ gcs, unsigned* __restrict__ bufd,
                               unsigned* __restrict__ bufs) {
    int blk = blockIdx.x;               // NE * NCH
    int e = blk / NCH, ch = blk % NCH;
    int tid = threadIdx.x;              // 256
    __shared__ int hd[CB], hs[CB], bd[CB], bs[CB];
    for (int i = tid; i < CB; i += 256) { hd[i] = 0; hs[i] = 0; }
    __syncthreads();
    const int* srcp = ei + (e * 2 + 0) * NEDGE;
    const int* dstp = ei + (e * 2 + 1) * NEDGE;
    int j0 = ch * CHUNK;
    int src[8], dst[8], rd[8], rs[8];
#pragma unroll
    for (int i = 0; i < 8; i++) {
        int j = j0 + i * 256 + tid;
        if (j < NEDGE) {
            src[i] = srcp[j]; dst[i] = dstp[j];
            rd[i] = atomicAdd(&hd[dst[i] >> 8], 1);
            rs[i] = atomicAdd(&hs[src[i] >> 8], 1);
        } else src[i] = -1;
    }
    __syncthreads();
    for (int i = tid; i < CB; i += 256) {
        bd[i] = hd[i] ? atomicAdd(&gcd[e * CB + i], hd[i]) : 0;
        bs[i] = hs[i] ? atomicAdd(&gcs[e * CB + i], hs[i]) : 0;
    }
    __syncthreads();
#pragma unroll
    for (int i = 0; i < 8; i++) {
        int j = j0 + i * 256 + tid;
        if (j < NEDGE) {
            int bn = dst[i] >> 8;
            int pd = bd[bn] + rd[i]; if (pd >= CAP) pd = CAP - 1;   // defensive
            bufd[((size_t)e * CB + bn) * CAP + pd] =
                ((unsigned)(dst[i] & 255) << 24) | (unsigned)src[i];
            bn = src[i] >> 8;
            int ps = bs[bn] + rs[i]; if (ps >= CAP) ps = CAP - 1;   // defensive
            bufs[((size_t)e * CB + bn) * CAP + ps] =
                ((unsigned)(src[i] & 255) << 19) | (unsigned)j;
        }
    }
}

// ---- coarse-offset scan (196 bins / edge type) + offs[NN] sentinel ----------
__global__ void cscan_kernel(const int* __restrict__ gcd, int* __restrict__ coff,
                             int* __restrict__ offs) {
    int e = blockIdx.x;                 // NE
    int tid = threadIdx.x;              // 256
    __shared__ int sb[256];
    int v = (tid < CB) ? gcd[e * CB + tid] : 0;
    sb[tid] = v; __syncthreads();
    for (int off = 1; off < 256; off <<= 1) {
        int a = (tid >= off) ? sb[tid - off] : 0;
        __syncthreads();
        sb[tid] += a;
        __syncthreads();
    }
    if (tid < CB) coff[e * (CB + 1) + tid] = sb[tid] - v;   // exclusive
    if (tid == CB - 1) coff[e * (CB + 1) + CB] = sb[tid];
    if (tid == 0) offs[e * (NN + 1) + NN] = NEDGE;
}

// ---- fine pass (dst): per-bucket exact CSR offs + dst-sorted srcb -----------
__global__ void fine_dst_kernel(const unsigned* __restrict__ bufd, const int* __restrict__ gcd,
                                const int* __restrict__ coff, int* __restrict__ offs,
                                int* __restrict__ srcb) {
    int blk = blockIdx.x;               // NE * CB
    int e = blk / CB, bn = blk % CB;
    int tid = threadIdx.x;              // 256
    int cnt = gcd[e * CB + bn]; if (cnt > CAP) cnt = CAP;
    int base = coff[e * (CB + 1) + bn];
    const unsigned* b = bufd + ((size_t)e * CB + bn) * CAP;
    __shared__ int dc[256], ss[256];
    dc[tid] = 0; __syncthreads();
    for (int i = tid; i < cnt; i += 256) atomicAdd(&dc[b[i] >> 24], 1);
    __syncthreads();
    int v = dc[tid];
    ss[tid] = v; __syncthreads();
    for (int off = 1; off < 256; off <<= 1) {
        int a = (tid >= off) ? ss[tid - off] : 0;
        __syncthreads();
        ss[tid] += a;
        __syncthreads();
    }
    int excl = ss[tid] - v;
    int d = bn * 256 + tid;
    if (d < NN) offs[e * (NN + 1) + d] = base + excl;
    dc[tid] = excl;                     // reuse as scatter cursor
    __syncthreads();
    for (int i = tid; i < cnt; i += 256) {
        unsigned w = b[i];
        int r = atomicAdd(&dc[w >> 24], 1);
        srcb[(size_t)e * NEDGE + base + r] = (int)(w & 0xFFFFFF);
    }
}

// ---- fine pass (src): per-src last-edge-index max -> ewsc -------------------
__global__ void fine_src_kernel(const unsigned* __restrict__ bufs, const int* __restrict__ gcs,
                                const void* __restrict__ ew, float* __restrict__ ewsc,
                                const int* __restrict__ flag) {
    int blk = blockIdx.x;               // NE * CB
    int e = blk / CB, bn = blk % CB;
    int tid = threadIdx.x;              // 256
    int cnt = gcs[e * CB + bn]; if (cnt > CAP) cnt = CAP;
    const unsigned* b = bufs + ((size_t)e * CB + bn) * CAP;
    __shared__ int mx[256];
    mx[tid] = -1; __syncthreads();
    for (int i = tid; i < cnt; i += 256) {
        unsigned w = b[i];
        atomicMax(&mx[w >> 19], (int)(w & 0x7FFFF));
    }
    __syncthreads();
    int n = bn * 256 + tid;
    if (n < NN) {
        int mj = mx[tid];
        float v = 1.0f;
        if (mj >= 0)
            v = sigm(*flag ? ((const float*)ew)[(size_t)e * NEDGE + mj]
                           : b2f(((const bf16*)ew)[(size_t)e * NEDGE + mj]));
        ewsc[e * NN + n] = v;           // src type of edge type e == e
    }
}

// ---- weight prep: transpose + fold rel into K/V weights ---------------------
// wT layout (bf16, [n][k]): mat 0,1 = linT; mat 2+lt*3+{0,1,2} = kT_fold,qT,vT_fold
// (lt = l*2+t); mat 14+lt = aT.
template <typename T>
__device__ __forceinline__ void prep_w_body(const T* lin_w, const T* k_w, const T* q_w,
                                            const T* v_w, const T* a_w, const T* rel_att,
                                            const T* rel_msg, unsigned short* wT) {
    int bid = blockIdx.x, tid = threadIdx.x;
    int mat = bid >> 6;
    int elem = (bid & 63) * 256 + tid;
    int n = elem >> 7, k = elem & 127;
    float v;
    if (mat < 2) {
        v = toF(lin_w[(size_t)mat * 16384 + k * 128 + n]);
    } else if (mat < 14) {
        int m2 = mat - 2, lt = m2 / 3, op = m2 % 3;
        if (op == 1) {
            v = toF(q_w[(size_t)lt * 16384 + k * 128 + n]);
        } else {
            const T* w = (op == 0 ? k_w : v_w) + (size_t)lt * 16384 + k * 128;
            const T* rl = (op == 0 ? rel_att : rel_msg) + (size_t)lt * 4096;  // e == t
            int hh = n >> 5, jj = n & 31;
            float s = 0.f;
#pragma unroll 8
            for (int d = 0; d < 32; d++)
                s += toF(w[hh * 32 + d]) * toF(rl[(hh * 32 + d) * 32 + jj]);
            v = s;
        }
    } else {
        v = toF(a_w[(size_t)(mat - 14) * 16384 + k * 128 + n]);
    }
    wT[(size_t)mat * 16384 + n * 128 + k] = f2bits(v);
}
__global__ void prep_w_kernel(const void* lin_w, const void* k_w, const void* q_w,
                              const void* v_w, const void* a_w, const void* rel_att,
                              const void* rel_msg, unsigned short* wT, const int* flag) {
    if (*flag) prep_w_body<float>((const float*)lin_w, (const float*)k_w, (const float*)q_w,
                                  (const float*)v_w, (const float*)a_w, (const float*)rel_att,
                                  (const float*)rel_msg, wT);
    else       prep_w_body<bf16>((const bf16*)lin_w, (const bf16*)k_w, (const bf16*)q_w,
                                 (const bf16*)v_w, (const bf16*)a_w, (const bf16*)rel_att,
                                 (const bf16*)rel_msg, wT);
}

// ---- bias prep (fp32) + rel_p + skip ----------------------------------------
template <typename T>
__device__ __forceinline__ void prep_misc_body(const T* lin_b, const T* k_b, const T* q_b,
                                               const T* v_b, const T* a_b, const T* rel_att,
                                               const T* rel_msg, const T* rel_p, const T* skip,
                                               float* biasall, float* relpf, float* skipf) {
    int mat = blockIdx.x, n = threadIdx.x;  // 18 x 128
    float v;
    if (mat < 2) {
        v = toF(lin_b[mat * 128 + n]);
    } else if (mat < 14) {
        int m2 = mat - 2, lt = m2 / 3, op = m2 % 3;
        if (op == 1) {
            v = toF(q_b[lt * 128 + n]);
        } else {
            const T* b = (op == 0 ? k_b : v_b) + lt * 128;
            const T* rl = (op == 0 ? rel_att : rel_msg) + (size_t)lt * 4096;
            int hh = n >> 5, jj = n & 31;
            float s = 0.f;
#pragma unroll 8
            for (int d = 0; d < 32; d++)
                s += toF(b[hh * 32 + d]) * toF(rl[(hh * 32 + d) * 32 + jj]);
            v = s;
        }
    } else {
        v = toF(a_b[(mat - 14) * 128 + n]);
    }
    biasall[mat * 128 + n] = v;
    if (mat == 0 && n < 16) relpf[n] = toF(rel_p[n]);
    if (mat == 1 && n < 4) skipf[n] = toF(skip[n]);
}
__global__ void prep_misc_kernel(const void* lin_b, const void* k_b, const void* q_b,
                                 const void* v_b, const void* a_b, const void* rel_att,
                                 const void* rel_msg, const void* rel_p, const void* skip,
                                 float* biasall, float* relpf, float* skipf, const int* flag) {
    if (*flag) prep_misc_body<float>((const float*)lin_b, (const float*)k_b, (const float*)q_b,
                                     (const float*)v_b, (const float*)a_b, (const float*)rel_att,
                                     (const float*)rel_msg, (const float*)rel_p, (const float*)skip,
                                     biasall, relpf, skipf);
    else       prep_misc_body<bf16>((const bf16*)lin_b, (const bf16*)k_b, (const bf16*)q_b,
                                    (const bf16*)v_b, (const bf16*)a_b, (const bf16*)rel_att,
                                    (const bf16*)rel_msg, (const bf16*)rel_p, (const bf16*)skip,
                                    biasall, relpf, skipf);
}

// ---- shared GEMM helpers ----------------------------------------------------
__device__ __forceinline__ void stage_w(unsigned short* __restrict__ Wl,
                                        const unsigned short* __restrict__ wmat, int tid) {
#pragma unroll
    for (int i = 0; i < 8; i++) {
        int c = i * 256 + tid;           // 2048 chunks of 8
        int n = c >> 4, ko = (c & 15) * 8;
        *(bf16x8*)&Wl[n * WPITCH + ko] = *(const bf16x8*)&wmat[n * 128 + ko];
    }
}

__device__ __forceinline__ void mfma_pass(const unsigned short* __restrict__ Wl,
                                          const bf16x8 af[4], const float* __restrict__ bias,
                                          f32x4 acc[8], int m16, int quad) {
#pragma unroll
    for (int ni = 0; ni < 8; ni++) {
        float b = bias[ni * 16 + m16];
        f32x4 iv = {b, b, b, b};
        acc[ni] = iv;
    }
#pragma unroll
    for (int ks = 0; ks < 4; ks++) {
        bf16x8 a = af[ks];
#pragma unroll
        for (int ni = 0; ni < 8; ni++) {
            bf16x8 bb = *(const bf16x8*)&Wl[(ni * 16 + m16) * WPITCH + ks * 32 + quad * 8];
            acc[ni] = __builtin_amdgcn_mfma_f32_16x16x32_bf16(a, bb, acc[ni], 0, 0, 0);
        }
    }
}

// kqv 3-pass GEMM on an LDS-staged A tile. hT may ALIAS Wl (rows 0..63): the
// af2 registers are loaded from hT before pass 0's barrier+restage overwrites
// Wl, and the pass-0 barrier (lgkmcnt-draining) orders those reads. Writes
// K/V interleaved + q with scalar 2B stores (L2 write-combines them; the
// vectorized LDS-bounce variant measured slower -- round-9 lesson).
__device__ __forceinline__ void kqv_passes(const unsigned short* __restrict__ hT,
                                           unsigned short* __restrict__ Wl,
                                           const unsigned short* __restrict__ wTall,
                                           const float* __restrict__ biasall, int lt,
                                           unsigned short* __restrict__ kv,
                                           unsigned short* __restrict__ qq,
                                           int t, int nb, int wave, int m16, int quad, int tid) {
    bf16x8 af2[4];
#pragma unroll
    for (int ks = 0; ks < 4; ks++)
        af2[ks] = *(const bf16x8*)&hT[(wave * 16 + m16) * WPITCH + ks * 32 + quad * 8];
    f32x4 acc[8];
#pragma unroll
    for (int pass = 0; pass < 3; pass++) {
        int mat = 2 + lt * 3 + pass;
        __syncthreads();   // prior reads of Wl/hT (incl. af2 loads) done before restage
        stage_w(Wl, wTall + (size_t)mat * 16384, tid);
        __syncthreads();
        mfma_pass(Wl, af2, biasall + mat * 128, acc, m16, quad);
#pragma unroll
        for (int r = 0; r < 4; r++) {
            int node = nb + wave * 16 + quad * 4 + r;
            if (node < NN) {
#pragma unroll
                for (int ni = 0; ni < 8; ni++) {
                    unsigned short hb = f2hbits(acc[ni][r]);
                    int c = ni * 16 + m16;
                    if (pass == 1) {
                        qq[((size_t)t * NN + node) * 128 + c] = hb;
                    } else {
                        size_t ro = ((size_t)t * NN + node) * 256 + (pass == 0 ? 0 : 128);
                        kv[ro + c] = hb;
                    }
                }
            }
        }
    }
}

// ---- fused lin + kqv(l=0): x -> h = relu(xW+b)*ewsc -> {K|V}, q -------------
// The transposed h tile is bounced through Wl's FIRST 64 ROWS (hT aliases Wl):
// after mfma_pass a barrier retires all waves' W-fragment reads, the tile is
// written, another barrier publishes it, af2 is read, and pass 0 restages Wl.
// LDS = Wl only (34816 B) -> 4 blocks/CU (was 52224 -> 3; occupancy 23%).
template <bool FP32>
__device__ __forceinline__ void lin_kqv_body(const void* __restrict__ x,
                                             const unsigned short* __restrict__ wTall,
                                             const float* __restrict__ biasall,
                                             const float* __restrict__ ewsc,
                                             float* __restrict__ h,
                                             unsigned short* __restrict__ kv,
                                             unsigned short* __restrict__ qq,
                                             unsigned short* __restrict__ Wl) {
    int bid = blockIdx.x, tid = threadIdx.x;
    int t = bid / MBLK64, nb = (bid % MBLK64) * 64;
    int wave = tid >> 6, lane = tid & 63;
    int m16 = lane & 15, quad = lane >> 4;
    stage_w(Wl, wTall + (size_t)t * 16384, tid);
    int arow = nb + wave * 16 + m16;
    int arc = arow < NN ? arow : NN - 1;
    size_t abase = ((size_t)t * NN + arc) * 128;
    bf16x8 af[4];
#pragma unroll
    for (int ks = 0; ks < 4; ks++) {
        if (FP32) {
            const float4* s = (const float4*)((const float*)x + abase + ks * 32 + quad * 8);
            float4 f0 = s[0], f1 = s[1];
            unsigned short* pu = (unsigned short*)&af[ks];
            pu[0] = f2bits(f0.x); pu[1] = f2bits(f0.y); pu[2] = f2bits(f0.z); pu[3] = f2bits(f0.w);
            pu[4] = f2bits(f1.x); pu[5] = f2bits(f1.y); pu[6] = f2bits(f1.z); pu[7] = f2bits(f1.w);
        } else {
            af[ks] = *(const bf16x8*)((const unsigned short*)x + abase + ks * 32 + quad * 8);
        }
    }
    __syncthreads();
    f32x4 acc[8];
    mfma_pass(Wl, af, biasall + t * 128, acc, m16, quad);
    __syncthreads();   // all waves done reading Wl B-frags -> safe to overwrite as hT
#pragma unroll
    for (int r = 0; r < 4; r++) {
        int rloc = wave * 16 + quad * 4 + r;
        int node = nb + rloc;
        float es = ewsc[t * NN + (node < NN ? node : NN - 1)];
#pragma unroll
        for (int ni = 0; ni < 8; ni++) {
            float v = fmaxf(acc[ni][r], 0.f) * es;
            unsigned short vb = (node < NN) ? f2bits(v) : (unsigned short)0;
            if (node < NN) h[((size_t)t * NN + node) * 128 + ni * 16 + m16] = v;
            Wl[rloc * WPITCH + ni * 16 + m16] = vb;   // hT aliases Wl rows 0..63
        }
    }
    __syncthreads();   // hT published
    kqv_passes(Wl, Wl, wTall, biasall, /*lt=*/t, kv, qq, t, nb, wave, m16, quad, tid);
}
__global__ void __launch_bounds__(256, 4) lin_kqv_gemm(const void* x,
                                                       const unsigned short* wTall,
                                                       const float* biasall, const float* ewsc,
                                                       float* h, unsigned short* kv,
                                                       unsigned short* qq, const int* flag) {
    __shared__ unsigned short Wl[128 * WPITCH];   // 34816 B -> 4 blocks/CU
    if (*flag) lin_kqv_body<true>(x, wTall, biasall, ewsc, h, kv, qq, Wl);
    else       lin_kqv_body<false>(x, wTall, biasall, ewsc, h, kv, qq, Wl);
}

// ---- merged-edge-type segment-softmax aggregation (r4-proven, at line-traffic
// roofline: 512 B/edge * 800k = 410 MB L2-line traffic @ ~6.4 TB/s = ~63 us) ---
__global__ void __launch_bounds__(256) agg_kernel(const unsigned short* __restrict__ qq,
                                                  const unsigned short* __restrict__ kv,
                                                  const int* __restrict__ srcb,
                                                  const int* __restrict__ offs,
                                                  const float* __restrict__ relpf, int l,
                                                  unsigned short* __restrict__ aggb) {
    int bid = blockIdx.x;
    int e = bid / AGGB;
    int wave = threadIdx.x >> 6, lane = threadIdx.x & 63;
    int stream = lane >> 4, l4 = lane & 15;
    int dst = (bid % AGGB) * 16 + wave * 4 + stream;
    int t = 1 - e;                      // EDGE_DST=(1,0)
    int le = l * 2 + e;
    int c0 = l4 * 8, head = l4 >> 2;
    const int* offs_e = offs + e * (NN + 1);
    const int* srcb_e = srcb + (size_t)e * NEDGE;
    int beg = offs_e[dst], end = offs_e[dst + 1];
    size_t rowo = ((size_t)t * NN + dst) * 128 + c0;
    float scale = relpf[le * 4 + head] * 0.17677669529663687f * 1.44269504088896f;
    uivec4 qraw = __builtin_nontemporal_load((const uivec4*)&qq[rowo]);
    f16x2 q[4];
#pragma unroll
    for (int i = 0; i < 4; i++) { unsigned w = qraw[i]; __builtin_memcpy(&q[i], &w, 4); }
    const unsigned short* kvb = kv + (size_t)e * NN * 256;  // EDGE_SRC=(0,1): s == e
    float lsum = 0.f;
    float acc[8] = {0.f, 0.f, 0.f, 0.f, 0.f, 0.f, 0.f, 0.f};
    int jmax = end - 1;
    for (int j0 = beg; j0 < end; j0 += 4) {
        int src[4];
#pragma unroll
        for (int i = 0; i < 4; i++) {
            int j = j0 + i;
            src[i] = __builtin_nontemporal_load(&srcb_e[j <= jmax ? j : jmax]);
        }
        uivec4 kr[4], vr[4];
#pragma unroll
        for (int i = 0; i < 4; i++) {
            size_t so = (size_t)src[i] * 256 + c0;
            kr[i] = *(const uivec4*)&kvb[so];
            vr[i] = *(const uivec4*)&kvb[so + 128];
        }
#pragma unroll
        for (int i = 0; i < 4; i++) {
            float p = dot8_f16((const unsigned*)&kr[i], q, 0.f);
            p += __shfl_xor(p, 1, 64);  // reduce 4 lanes = 32 chans = one head
            p += __shfl_xor(p, 2, 64);
            float es = (j0 + i <= jmax) ? exp2f(p * scale) : 0.f;
            lsum += es;
            const unsigned* vu = (const unsigned*)&vr[i];
#pragma unroll
            for (int k = 0; k < 4; k++) {
                f16x2 vh; __builtin_memcpy(&vh, &vu[k], 4);
                acc[k * 2]     += es * (float)vh.x;
                acc[k * 2 + 1] += es * (float)vh.y;
            }
        }
    }
    float inv = 1.0f / (lsum + 1e-16f);
    unsigned short o[8];
#pragma unroll
    for (int i = 0; i < 8; i++) o[i] = f2bits(acc[i] * inv);
    *(bf16x8*)&aggb[rowo] = *(bf16x8*)o;   // all 64 lanes: 4 rows x 256B coalesced
}

// ---- fused outproj(l) + kqv(l+1): h' = beta*(gelu(agg)Wa+ba)+(1-beta)*h -----
// h' tile bounced through Wl rows 0..63 (hT aliases Wl, same as lin_kqv).
// aggb aliases qq: each block reads its own aggb rows before its kqv pass
// rewrites the same rows (block-private rows, barrier-ordered).
__global__ void __launch_bounds__(256, 4) outproj_kqv_gemm(const unsigned short* __restrict__ aggb,
                                                           const unsigned short* __restrict__ wTall,
                                                           const float* __restrict__ biasall,
                                                           const float* __restrict__ skipf, int l,
                                                           float* __restrict__ h,
                                                           unsigned short* __restrict__ kv,
                                                           unsigned short* __restrict__ qq) {
    __shared__ unsigned short Wl[128 * WPITCH];   // 34816 B -> 4 blocks/CU
    int bid = blockIdx.x, tid = threadIdx.x;
    int t = bid / MBLK64, nb = (bid % MBLK64) * 64;
    int lt = l * 2 + t;
    int wave = tid >> 6, lane = tid & 63;
    int m16 = lane & 15, quad = lane >> 4;
    int mat = 14 + lt;
    stage_w(Wl, wTall + (size_t)mat * 16384, tid);
    int arow = nb + wave * 16 + m16;
    int arc = arow < NN ? arow : NN - 1;
    size_t abase = ((size_t)t * NN + arc) * 128;
    bf16x8 af[4];
#pragma unroll
    for (int ks = 0; ks < 4; ks++) {
        bf16x8 raw = *(const bf16x8*)&aggb[abase + ks * 32 + quad * 8];
        const unsigned short* ru = (const unsigned short*)&raw;
        unsigned short* pu = (unsigned short*)&af[ks];
#pragma unroll
        for (int jj = 0; jj < 8; jj++) {
            float g = bits2f(ru[jj]);
            pu[jj] = f2bits(0.5f * g * (1.0f + erff(g * 0.70710678118654752f)));  // exact gelu
        }
    }
    __syncthreads();
    f32x4 acc[8];
    mfma_pass(Wl, af, biasall + mat * 128, acc, m16, quad);
    float beta = sigm(skipf[lt]);
    __syncthreads();   // all waves done reading Wl B-frags -> safe to overwrite as hT
#pragma unroll
    for (int r = 0; r < 4; r++) {
        int rloc = wave * 16 + quad * 4 + r;
        int node = nb + rloc;
#pragma unroll
        for (int ni = 0; ni < 8; ni++) {
            unsigned short vb = 0;
            if (node < NN) {
                size_t io = ((size_t)t * NN + node) * 128 + ni * 16 + m16;
                float nv = beta * acc[ni][r] + (1.0f - beta) * h[io];
                h[io] = nv;
                vb = f2bits(nv);
            }
            Wl[rloc * WPITCH + ni * 16 + m16] = vb;   // hT aliases Wl rows 0..63
        }
    }
    __syncthreads();   // hT published
    kqv_passes(Wl, Wl, wTall, biasall, /*lt=*/(l + 1) * 2 + t, kv, qq, t, nb, wave, m16, quad, tid);
}

// ---- plain outproj for the last layer: writes the final output --------------
// h store is DEAD at the last layer (h never read again) -> skipped (saves
// 51.2 MB of writes).
__global__ void __launch_bounds__(256, 4) outproj_gemm(const unsigned short* __restrict__ aggb,
                                                       const unsigned short* __restrict__ wTall,
                                                       const float* __restrict__ biasall,
                                                       const float* __restrict__ skipf, int l,
                                                       float* __restrict__ h, int last,
                                                       void* __restrict__ outp,
                                                       const int* __restrict__ flag) {
    __shared__ unsigned short Wl[128 * WPITCH];
    int bid = blockIdx.x, tid = threadIdx.x;
    int t = bid / MBLK64, nb = (bid % MBLK64) * 64;
    int lt = l * 2 + t;
    int wave = tid >> 6, lane = tid & 63;
    int m16 = lane & 15, quad = lane >> 4;
    int mat = 14 + lt;
    stage_w(Wl, wTall + (size_t)mat * 16384, tid);
    int arow = nb + wave * 16 + m16;
    int arc = arow < NN ? arow : NN - 1;
    size_t abase = ((size_t)t * NN + arc) * 128;
    bf16x8 af[4];
#pragma unroll
    for (int ks = 0; ks < 4; ks++) {
        bf16x8 raw = *(const bf16x8*)&aggb[abase + ks * 32 + quad * 8];
        const unsigned short* ru = (const unsigned short*)&raw;
        unsigned short* pu = (unsigned short*)&af[ks];
#pragma unroll
        for (int jj = 0; jj < 8; jj++) {
            float g = bits2f(ru[jj]);
            pu[jj] = f2bits(0.5f * g * (1.0f + erff(g * 0.70710678118654752f)));  // exact gelu
        }
    }
    __syncthreads();
    f32x4 acc[8];
    mfma_pass(Wl, af, biasall + mat * 128, acc, m16, quad);
    float beta = sigm(skipf[lt]);
    int fl = *flag;
#pragma unroll
    for (int r = 0; r < 4; r++) {
        int node = nb + wave * 16 + quad * 4 + r;
        if (node < NN) {
            size_t ro = ((size_t)t * NN + node) * 128;
#pragma unroll
            for (int ni = 0; ni < 8; ni++) {
                size_t io = ro + ni * 16 + m16;
                float nv = beta * acc[ni][r] + (1.0f - beta) * h[io];
                if (!last) h[io] = nv;
                if (last) {
                    if (fl) ((float*)outp)[io] = nv;
                    else    ((bf16*)outp)[io] = __float2bfloat16(nv);
                }
            }
        }
    }
}

extern "C" void kernel_launch(void* const* d_in, const int* in_sizes, int n_in,
                              void* d_out, int out_size, void* d_ws, size_t ws_size,
                              hipStream_t stream) {
    const void* x      = d_in[0];
    const int*  ei     = (const int*)d_in[1];
    const void* ew     = d_in[2];
    const void* lin_w  = d_in[3];
    const void* lin_b  = d_in[4];
    const void* k_w    = d_in[5];
    const void* k_b    = d_in[6];
    const void* q_w    = d_in[7];
    const void* q_b    = d_in[8];
    const void* v_w    = d_in[9];
    const void* v_b    = d_in[10];
    const void* a_w    = d_in[11];
    const void* a_b    = d_in[12];
    const void* skip   = d_in[13];
    const void* rel_att = d_in[14];
    const void* rel_msg = d_in[15];
    const void* rel_p  = d_in[16];

    char* p = (char*)d_ws;
    auto alloc = [&](size_t bytes) -> char* {
        char* r = p;
        p += (bytes + 255) & ~(size_t)255;
        return r;
    };
    int* flag     = (int*)alloc(sizeof(int));
    int* gcd      = (int*)alloc(sizeof(int) * NE * CB);
    int* gcs      = (int*)alloc(sizeof(int) * NE * CB);
    int* coff     = (int*)alloc(sizeof(int) * NE * (CB + 1));
    int* offs     = (int*)alloc(sizeof(int) * NE * (NN + 1));
    int* srcb     = (int*)alloc(sizeof(int) * NE * NEDGE);
    unsigned* bufd = (unsigned*)alloc(sizeof(unsigned) * NE * CB * CAP);   // 6.4 MB
    unsigned* bufs = (unsigned*)alloc(sizeof(unsigned) * NE * CB * CAP);   // 6.4 MB
    unsigned short* wTall = (unsigned short*)alloc(sizeof(short) * 18 * 16384);
    float* biasall = (float*)alloc(sizeof(float) * 18 * 128);
    float* relpf   = (float*)alloc(sizeof(float) * 16);
    float* skipf   = (float*)alloc(sizeof(float) * 4);
    float* ewsc    = (float*)alloc(sizeof(float) * NT * NN);
    float* h       = (float*)alloc(sizeof(float) * NT * NN * HID);               // 51.2 MB fp32
    unsigned short* qq = (unsigned short*)alloc(sizeof(short) * NT * NN * HID);  // fp16 (aggb aliases)
    unsigned short* kv = (unsigned short*)alloc(sizeof(short) * NT * NN * HID * 2); // fp16 [K|V] interleaved
    unsigned short* aggb = qq;

    detect_kernel<<<1, 64, 0, stream>>>(x, flag, gcd, gcs);
    bucket1_kernel<<<NE * NCH, 256, 0, stream>>>(ei, gcd, gcs, bufd, bufs);
    cscan_kernel<<<NE, 256, 0, stream>>>(gcd, coff, offs);
    fine_dst_kernel<<<NE * CB, 256, 0, stream>>>(bufd, gcd, coff, offs, srcb);
    fine_src_kernel<<<NE * CB, 256, 0, stream>>>(bufs, gcs, ew, ewsc, flag);
    prep_w_kernel<<<18 * 64, 256, 0, stream>>>(lin_w, k_w, q_w, v_w, a_w, rel_att, rel_msg,
                                               wTall, flag);
    prep_misc_kernel<<<18, 128, 0, stream>>>(lin_b, k_b, q_b, v_b, a_b, rel_att, rel_msg,
                                             rel_p, skip, biasall, relpf, skipf, flag);

    // fused pipeline: lin+kqv(0) -> agg(0) -> outproj(0)+kqv(1) -> agg(1) -> outproj(1,last)
    lin_kqv_gemm<<<NT * MBLK64, 256, 0, stream>>>(x, wTall, biasall, ewsc, h, kv, qq, flag);
    agg_kernel<<<NE * AGGB, 256, 0, stream>>>(qq, kv, srcb, offs, relpf, 0, aggb);
    outproj_kqv_gemm<<<NT * MBLK64, 256, 0, stream>>>(aggb, wTall, biasall, skipf, 0, h, kv, qq);
    agg_kernel<<<NE * AGGB, 256, 0, stream>>>(qq, kv, srcb, offs, relpf, 1, aggb);
    outproj_gemm<<<NT * MBLK64, 256, 0, stream>>>(aggb, wTall, biasall, skipf, 1, h, 1,
                                                  d_out, flag);
}

// Round 13
// 410.922 us; speedup vs baseline: 1.0886x; 1.0148x over previous
//
#include <hip/hip_runtime.h>
#include <hip/hip_bf16.h>
#include <math.h>

typedef __hip_bfloat16 bf16;
typedef _Float16 f16;
typedef __attribute__((ext_vector_type(2))) _Float16 f16x2;
typedef __attribute__((ext_vector_type(8))) short bf16x8;   // MFMA A/B frag (4 VGPRs)
typedef __attribute__((ext_vector_type(4))) float f32x4;    // MFMA C/D frag
typedef __attribute__((ext_vector_type(4))) unsigned uivec4; // native u32x4 (nontemporal-ok)

#define NT 2
#define NE 2
#define NN 50000
#define HID 128
#define NH 4
#define DD 32
#define NL 2
#define NEDGE 400000
#define MBLK64 782      // ceil(50000/64)
#define AGGB 3125       // NN/16 (16 dsts per block: 4 waves x 4 streams, 1 dst/stream)
#define WPITCH 136      // LDS row pitch (elems): 272 B, 16B-aligned, bank-uniform b128
#define CB 196          // coarse buckets (key >> 8), covers 50176 nodes
#define CAP 4096        // bucket capacity (expected 2040, +45 sigma margin)
#define CHUNK 2048      // edges per bucket1 block
#define NCH 196         // ceil(NEDGE / CHUNK)

__device__ __forceinline__ float b2f(bf16 v) { return __bfloat162float(v); }
__device__ __forceinline__ float toF(float v) { return v; }
__device__ __forceinline__ float toF(bf16 v) { return b2f(v); }
__device__ __forceinline__ float sigm(float x) { return 1.0f / (1.0f + __expf(-x)); }
__device__ __forceinline__ unsigned short f2bits(float f) {
    bf16 h = __float2bfloat16(f);
    unsigned short b; __builtin_memcpy(&b, &h, 2); return b;
}
__device__ __forceinline__ float bits2f(unsigned short b) {
    unsigned u = ((unsigned)b) << 16; float f; __builtin_memcpy(&f, &u, 4); return f;
}
__device__ __forceinline__ unsigned short f2hbits(float f) {
    f16 h = (f16)f;
    unsigned short b; __builtin_memcpy(&b, &h, 2); return b;
}

__device__ __forceinline__ float dot8_f16(const unsigned* kr, const f16x2 q[4], float init) {
    float p = init;
#pragma unroll
    for (int i = 0; i < 4; i++) {
        f16x2 kh; __builtin_memcpy(&kh, &kr[i], 4);
#if __has_builtin(__builtin_amdgcn_fdot2)
        p = __builtin_amdgcn_fdot2(q[i], kh, p, false);
#else
        p += (float)q[i].x * (float)kh.x + (float)q[i].y * (float)kh.y;
#endif
    }
    return p;
}

// ---- input dtype detection (0 = bf16, 1 = fp32) + gcd/gcs zeroing -----------
__global__ void detect_kernel(const void* __restrict__ x, int* __restrict__ flag,
                              int* __restrict__ gcd, int* __restrict__ gcs) {
    int lane = threadIdx.x;  // 64
    for (int i = lane; i < NE * CB; i += 64) { gcd[i] = 0; gcs[i] = 0; }
    const unsigned short* u = (const unsigned short*)x;
    int cnt = 0;
    for (int i = 0; i < 4; i++) {
        unsigned short w = u[lane * 4 + i];
        int e = (w >> 7) & 0xFF;
        if (e >= 110 && e <= 135) cnt++;
    }
    for (int off = 32; off > 0; off >>= 1) cnt += __shfl_xor(cnt, off, 64);
    if (lane == 0) *flag = (cnt > 200) ? 0 : 1;
}

// ---- coarse bucketing: one edge pass, dst-keyed + src-keyed -----------------
__global__ void bucket1_kernel(const int* __restrict__ ei, int* __restrict__ gcd,
                               int* __restrict__ gcs, unsigned* __restrict__ bufd,
                               unsigned* __restrict__ bufs) {
    int blk = blockIdx.x;               // NE * NCH
    int e = blk / NCH, ch = blk % NCH;
    int tid = threadIdx.x;              // 256
    __shared__ int hd[CB], hs[CB], bd[CB], bs[CB];
    for (int i = tid; i < CB; i += 256) { hd[i] = 0; hs[i] = 0; }
    __syncthreads();
    const int* srcp = ei + (e * 2 + 0) * NEDGE;
    const int* dstp = ei + (e * 2 + 1) * NEDGE;
    int j0 = ch * CHUNK;
    int src[8], dst[8], rd[8], rs[8];
#pragma unroll
    for (int i = 0; i < 8; i++) {
        int j = j0 + i * 256 + tid;
        if (j < NEDGE) {
            src[i] = srcp[j]; dst[i] = dstp[j];
            rd[i] = atomicAdd(&hd[dst[i] >> 8], 1);
            rs[i] = atomicAdd(&hs[src[i] >> 8], 1);
        } else src[i] = -1;
    }
    __syncthreads();
    for (int i = tid; i < CB; i += 256) {
        bd[i] = hd[i] ? atomicAdd(&gcd[e * CB + i], hd[i]) : 0;
        bs[i] = hs[i] ? atomicAdd(&gcs[e * CB + i], hs[i]) : 0;
    }
    __syncthreads();
#pragma unroll
    for (int i = 0; i < 8; i++) {
        int j = j0 + i * 256 + tid;
        if (j < NEDGE) {
            int bn = dst[i] >> 8;
            int pd = bd[bn] + rd[i]; if (pd >= CAP) pd = CAP - 1;   // defensive
            bufd[((size_t)e * CB + bn) * CAP + pd] =
                ((unsigned)(dst[i] & 255) << 24) | (unsigned)src[i];
            bn = src[i] >> 8;
            int ps = bs[bn] + rs[i]; if (ps >= CAP) ps = CAP - 1;   // defensive
            bufs[((size_t)e * CB + bn) * CAP + ps] =
                ((unsigned)(src[i] & 255) << 19) | (unsigned)j;
        }
    }
}

// ---- combined fine pass (launch-merged; round-12 launch-count reduction) ----
// blk < NE*CB: dst role -- per-bucket exact CSR offs + dst-sorted srcb. The
//   coarse base (old cscan's coff) is recomputed per block as a 196-element
//   LDS tree-sum over gcd (cheap; deletes the nearly-empty cscan dispatch).
// blk >= NE*CB: src role -- per-src last-edge-index max -> ewsc.
__global__ void fine_kernel(const unsigned* __restrict__ bufd,
                            const unsigned* __restrict__ bufs,
                            const int* __restrict__ gcd, const int* __restrict__ gcs,
                            const void* __restrict__ ew, int* __restrict__ offs,
                            int* __restrict__ srcb, float* __restrict__ ewsc,
                            const int* __restrict__ flag) {
    int blk = blockIdx.x;               // 2 * NE * CB
    int tid = threadIdx.x;              // 256
    __shared__ int dc[256], ss[256];
    if (blk < NE * CB) {
        // ---------------- dst role ----------------
        int e = blk / CB, bn = blk % CB;
        int cntr = gcd[e * CB + bn];
        int cnt = cntr > CAP ? CAP : cntr;
        // base = sum of gcd[e*CB + i] for i < bn (exclusive coarse prefix)
        ss[tid] = (tid < bn) ? gcd[e * CB + tid] : 0;
        __syncthreads();
        for (int off = 128; off > 0; off >>= 1) {
            if (tid < off) ss[tid] += ss[tid + off];
            __syncthreads();
        }
        int base = ss[0];
        __syncthreads();
        if (tid == 0 && bn == 0) offs[e * (NN + 1) + NN] = NEDGE;   // sentinel
        const unsigned* b = bufd + ((size_t)e * CB + bn) * CAP;
        dc[tid] = 0; __syncthreads();
        for (int i = tid; i < cnt; i += 256) atomicAdd(&dc[b[i] >> 24], 1);
        __syncthreads();
        int v = dc[tid];
        ss[tid] = v; __syncthreads();
        for (int off = 1; off < 256; off <<= 1) {
            int a = (tid >= off) ? ss[tid - off] : 0;
            __syncthreads();
            ss[tid] += a;
            __syncthreads();
        }
        int excl = ss[tid] - v;
        int d = bn * 256 + tid;
        if (d < NN) offs[e * (NN + 1) + d] = base + excl;
        dc[tid] = excl;                 // reuse as scatter cursor
        __syncthreads();
        for (int i = tid; i < cnt; i += 256) {
            unsigned w = b[i];
            int r = atomicAdd(&dc[w >> 24], 1);
            srcb[(size_t)e * NEDGE + base + r] = (int)(w & 0xFFFFFF);
        }
    } else {
        // ---------------- src role ----------------
        int blk2 = blk - NE * CB;
        int e = blk2 / CB, bn = blk2 % CB;
        int cnt = gcs[e * CB + bn]; if (cnt > CAP) cnt = CAP;
        const unsigned* b = bufs + ((size_t)e * CB + bn) * CAP;
        dc[tid] = -1; __syncthreads();
        for (int i = tid; i < cnt; i += 256) {
            unsigned w = b[i];
            atomicMax(&dc[w >> 19], (int)(w & 0x7FFFF));
        }
        __syncthreads();
        int n = bn * 256 + tid;
        if (n < NN) {
            int mj = dc[tid];
            float v = 1.0f;
            if (mj >= 0)
                v = sigm(*flag ? ((const float*)ew)[(size_t)e * NEDGE + mj]
                               : b2f(((const bf16*)ew)[(size_t)e * NEDGE + mj]));
            ewsc[e * NN + n] = v;       // src type of edge type e == e
        }
    }
}

// ---- weight prep (+ bias/rel_p/skip prep, launch-merged) --------------------
// wT layout (bf16, [n][k]): mat 0,1 = linT; mat 2+lt*3+{0,1,2} = kT_fold,qT,vT_fold
// (lt = l*2+t); mat 14+lt = aT. Blocks >= 18*64 do the misc (bias) prep.
template <typename T>
__device__ __forceinline__ void prep_w_body(const T* lin_w, const T* k_w, const T* q_w,
                                            const T* v_w, const T* a_w, const T* rel_att,
                                            const T* rel_msg, unsigned short* wT) {
    int bid = blockIdx.x, tid = threadIdx.x;
    int mat = bid >> 6;
    int elem = (bid & 63) * 256 + tid;
    int n = elem >> 7, k = elem & 127;
    float v;
    if (mat < 2) {
        v = toF(lin_w[(size_t)mat * 16384 + k * 128 + n]);
    } else if (mat < 14) {
        int m2 = mat - 2, lt = m2 / 3, op = m2 % 3;
        if (op == 1) {
            v = toF(q_w[(size_t)lt * 16384 + k * 128 + n]);
        } else {
            const T* w = (op == 0 ? k_w : v_w) + (size_t)lt * 16384 + k * 128;
            const T* rl = (op == 0 ? rel_att : rel_msg) + (size_t)lt * 4096;  // e == t
            int hh = n >> 5, jj = n & 31;
            float s = 0.f;
#pragma unroll 8
            for (int d = 0; d < 32; d++)
                s += toF(w[hh * 32 + d]) * toF(rl[(hh * 32 + d) * 32 + jj]);
            v = s;
        }
    } else {
        v = toF(a_w[(size_t)(mat - 14) * 16384 + k * 128 + n]);
    }
    wT[(size_t)mat * 16384 + n * 128 + k] = f2bits(v);
}
template <typename T>
__device__ __forceinline__ void prep_misc_body(const T* lin_b, const T* k_b, const T* q_b,
                                               const T* v_b, const T* a_b, const T* rel_att,
                                               const T* rel_msg, const T* rel_p, const T* skip,
                                               float* biasall, float* relpf, float* skipf,
                                               int mat, int n) {
    float v;
    if (mat < 2) {
        v = toF(lin_b[mat * 128 + n]);
    } else if (mat < 14) {
        int m2 = mat - 2, lt = m2 / 3, op = m2 % 3;
        if (op == 1) {
            v = toF(q_b[lt * 128 + n]);
        } else {
            const T* b = (op == 0 ? k_b : v_b) + lt * 128;
            const T* rl = (op == 0 ? rel_att : rel_msg) + (size_t)lt * 4096;
            int hh = n >> 5, jj = n & 31;
            float s = 0.f;
#pragma unroll 8
            for (int d = 0; d < 32; d++)
                s += toF(b[hh * 32 + d]) * toF(rl[(hh * 32 + d) * 32 + jj]);
            v = s;
        }
    } else {
        v = toF(a_b[(mat - 14) * 128 + n]);
    }
    biasall[mat * 128 + n] = v;
    if (mat == 0 && n < 16) relpf[n] = toF(rel_p[n]);
    if (mat == 1 && n < 4) skipf[n] = toF(skip[n]);
}
__global__ void prep_w_kernel(const void* lin_w, const void* k_w, const void* q_w,
                              const void* v_w, const void* a_w,
                              const void* lin_b, const void* k_b, const void* q_b,
                              const void* v_b, const void* a_b,
                              const void* rel_att, const void* rel_msg,
                              const void* rel_p, const void* skip,
                              unsigned short* wT, float* biasall, float* relpf,
                              float* skipf, const int* flag) {
    int bid = blockIdx.x;               // 18*64 + 18
    if (bid < 18 * 64) {
        if (*flag) prep_w_body<float>((const float*)lin_w, (const float*)k_w, (const float*)q_w,
                                      (const float*)v_w, (const float*)a_w, (const float*)rel_att,
                                      (const float*)rel_msg, wT);
        else       prep_w_body<bf16>((const bf16*)lin_w, (const bf16*)k_w, (const bf16*)q_w,
                                     (const bf16*)v_w, (const bf16*)a_w, (const bf16*)rel_att,
                                     (const bf16*)rel_msg, wT);
    } else {
        int mat = bid - 18 * 64, n = threadIdx.x;
        if (n < 128) {
            if (*flag) prep_misc_body<float>((const float*)lin_b, (const float*)k_b,
                                             (const float*)q_b, (const float*)v_b,
                                             (const float*)a_b, (const float*)rel_att,
                                             (const float*)rel_msg, (const float*)rel_p,
                                             (const float*)skip, biasall, relpf, skipf, mat, n);
            else       prep_misc_body<bf16>((const bf16*)lin_b, (const bf16*)k_b,
                                            (const bf16*)q_b, (const bf16*)v_b,
                                            (const bf16*)a_b, (const bf16*)rel_att,
                                            (const bf16*)rel_msg, (const bf16*)rel_p,
                                            (const bf16*)skip, biasall, relpf, skipf, mat, n);
        }
    }
}

// ---- shared GEMM helpers ----------------------------------------------------
__device__ __forceinline__ void stage_w(unsigned short* __restrict__ Wl,
                                        const unsigned short* __restrict__ wmat, int tid) {
#pragma unroll
    for (int i = 0; i < 8; i++) {
        int c = i * 256 + tid;           // 2048 chunks of 8
        int n = c >> 4, ko = (c & 15) * 8;
        *(bf16x8*)&Wl[n * WPITCH + ko] = *(const bf16x8*)&wmat[n * 128 + ko];
    }
}

__device__ __forceinline__ void mfma_pass(const unsigned short* __restrict__ Wl,
                                          const bf16x8 af[4], const float* __restrict__ bias,
                                          f32x4 acc[8], int m16, int quad) {
#pragma unroll
    for (int ni = 0; ni < 8; ni++) {
        float b = bias[ni * 16 + m16];
        f32x4 iv = {b, b, b, b};
        acc[ni] = iv;
    }
#pragma unroll
    for (int ks = 0; ks < 4; ks++) {
        bf16x8 a = af[ks];
#pragma unroll
        for (int ni = 0; ni < 8; ni++) {
            bf16x8 bb = *(const bf16x8*)&Wl[(ni * 16 + m16) * WPITCH + ks * 32 + quad * 8];
            acc[ni] = __builtin_amdgcn_mfma_f32_16x16x32_bf16(a, bb, acc[ni], 0, 0, 0);
        }
    }
}

// kqv 3-pass GEMM on an LDS-staged A tile. hT may ALIAS Wl (rows 0..63): the
// af2 registers are loaded from hT before pass 0's barrier+restage overwrites
// Wl, and the pass-0 barrier (lgkmcnt-draining) orders those reads. Writes
// K/V interleaved + q with scalar 2B stores (L2 write-combines them; the
// vectorized LDS-bounce variant measured slower -- round-9 lesson).
__device__ __forceinline__ void kqv_passes(const unsigned short* __restrict__ hT,
                                           unsigned short* __restrict__ Wl,
                                           const unsigned short* __restrict__ wTall,
                                           const float* __restrict__ biasall, int lt,
                                           unsigned short* __restrict__ kv,
                                           unsigned short* __restrict__ qq,
                                           int t, int nb, int wave, int m16, int quad, int tid) {
    bf16x8 af2[4];
#pragma unroll
    for (int ks = 0; ks < 4; ks++)
        af2[ks] = *(const bf16x8*)&hT[(wave * 16 + m16) * WPITCH + ks * 32 + quad * 8];
    f32x4 acc[8];
#pragma unroll
    for (int pass = 0; pass < 3; pass++) {
        int mat = 2 + lt * 3 + pass;
        __syncthreads();   // prior reads of Wl/hT (incl. af2 loads) done before restage
        stage_w(Wl, wTall + (size_t)mat * 16384, tid);
        __syncthreads();
        mfma_pass(Wl, af2, biasall + mat * 128, acc, m16, quad);
#pragma unroll
        for (int r = 0; r < 4; r++) {
            int node = nb + wave * 16 + quad * 4 + r;
            if (node < NN) {
#pragma unroll
                for (int ni = 0; ni < 8; ni++) {
                    unsigned short hb = f2hbits(acc[ni][r]);
                    int c = ni * 16 + m16;
                    if (pass == 1) {
                        qq[((size_t)t * NN + node) * 128 + c] = hb;
                    } else {
                        size_t ro = ((size_t)t * NN + node) * 256 + (pass == 0 ? 0 : 128);
                        kv[ro + c] = hb;
                    }
                }
            }
        }
    }
}

// ---- fused lin + kqv(l=0): x -> h = relu(xW+b)*ewsc -> {K|V}, q -------------
// The transposed h tile is bounced through Wl's FIRST 64 ROWS (hT aliases Wl):
// after mfma_pass a barrier retires all waves' W-fragment reads, the tile is
// written, another barrier publishes it, af2 is read, and pass 0 restages Wl.
// LDS = Wl only (34816 B) -> 4 blocks/CU.
template <bool FP32>
__device__ __forceinline__ void lin_kqv_body(const void* __restrict__ x,
                                             const unsigned short* __restrict__ wTall,
                                             const float* __restrict__ biasall,
                                             const float* __restrict__ ewsc,
                                             float* __restrict__ h,
                                             unsigned short* __restrict__ kv,
                                             unsigned short* __restrict__ qq,
                                             unsigned short* __restrict__ Wl) {
    int bid = blockIdx.x, tid = threadIdx.x;
    int t = bid / MBLK64, nb = (bid % MBLK64) * 64;
    int wave = tid >> 6, lane = tid & 63;
    int m16 = lane & 15, quad = lane >> 4;
    stage_w(Wl, wTall + (size_t)t * 16384, tid);
    int arow = nb + wave * 16 + m16;
    int arc = arow < NN ? arow : NN - 1;
    size_t abase = ((size_t)t * NN + arc) * 128;
    bf16x8 af[4];
#pragma unroll
    for (int ks = 0; ks < 4; ks++) {
        if (FP32) {
            const float4* s = (const float4*)((const float*)x + abase + ks * 32 + quad * 8);
            float4 f0 = s[0], f1 = s[1];
            unsigned short* pu = (unsigned short*)&af[ks];
            pu[0] = f2bits(f0.x); pu[1] = f2bits(f0.y); pu[2] = f2bits(f0.z); pu[3] = f2bits(f0.w);
            pu[4] = f2bits(f1.x); pu[5] = f2bits(f1.y); pu[6] = f2bits(f1.z); pu[7] = f2bits(f1.w);
        } else {
            af[ks] = *(const bf16x8*)((const unsigned short*)x + abase + ks * 32 + quad * 8);
        }
    }
    __syncthreads();
    f32x4 acc[8];
    mfma_pass(Wl, af, biasall + t * 128, acc, m16, quad);
    __syncthreads();   // all waves done reading Wl B-frags -> safe to overwrite as hT
#pragma unroll
    for (int r = 0; r < 4; r++) {
        int rloc = wave * 16 + quad * 4 + r;
        int node = nb + rloc;
        float es = ewsc[t * NN + (node < NN ? node : NN - 1)];
#pragma unroll
        for (int ni = 0; ni < 8; ni++) {
            float v = fmaxf(acc[ni][r], 0.f) * es;
            unsigned short vb = (node < NN) ? f2bits(v) : (unsigned short)0;
            if (node < NN) h[((size_t)t * NN + node) * 128 + ni * 16 + m16] = v;
            Wl[rloc * WPITCH + ni * 16 + m16] = vb;   // hT aliases Wl rows 0..63
        }
    }
    __syncthreads();   // hT published
    kqv_passes(Wl, Wl, wTall, biasall, /*lt=*/t, kv, qq, t, nb, wave, m16, quad, tid);
}
__global__ void __launch_bounds__(256, 4) lin_kqv_gemm(const void* x,
                                                       const unsigned short* wTall,
                                                       const float* biasall, const float* ewsc,
                                                       float* h, unsigned short* kv,
                                                       unsigned short* qq, const int* flag) {
    __shared__ unsigned short Wl[128 * WPITCH];   // 34816 B -> 4 blocks/CU
    if (*flag) lin_kqv_body<true>(x, wTall, biasall, ewsc, h, kv, qq, Wl);
    else       lin_kqv_body<false>(x, wTall, biasall, ewsc, h, kv, qq, Wl);
}

// ---- merged-edge-type segment-softmax aggregation (r4-proven, at line-traffic
// roofline: 512 B/edge * 800k = 410 MB L2-line traffic @ ~6.6 TB/s = ~62 us) ---
__global__ void __launch_bounds__(256) agg_kernel(const unsigned short* __restrict__ qq,
                                                  const unsigned short* __restrict__ kv,
                                                  const int* __restrict__ srcb,
                                                  const int* __restrict__ offs,
                                                  const float* __restrict__ relpf, int l,
                                                  unsigned short* __restrict__ aggb) {
    int bid = blockIdx.x;
    int e = bid / AGGB;
    int wave = threadIdx.x >> 6, lane = threadIdx.x & 63;
    int stream = lane >> 4, l4 = lane & 15;
    int dst = (bid % AGGB) * 16 + wave * 4 + stream;
    int t = 1 - e;                      // EDGE_DST=(1,0)
    int le = l * 2 + e;
    int c0 = l4 * 8, head = l4 >> 2;
    const int* offs_e = offs + e * (NN + 1);
    const int* srcb_e = srcb + (size_t)e * NEDGE;
    int beg = offs_e[dst], end = offs_e[dst + 1];
    size_t rowo = ((size_t)t * NN + dst) * 128 + c0;
    float scale = relpf[le * 4 + head] * 0.17677669529663687f * 1.44269504088896f;
    uivec4 qraw = __builtin_nontemporal_load((const uivec4*)&qq[rowo]);
    f16x2 q[4];
#pragma unroll
    for (int i = 0; i < 4; i++) { unsigned w = qraw[i]; __builtin_memcpy(&q[i], &w, 4); }
    const unsigned short* kvb = kv + (size_t)e * NN * 256;  // EDGE_SRC=(0,1): s == e
    float lsum = 0.f;
    float acc[8] = {0.f, 0.f, 0.f, 0.f, 0.f, 0.f, 0.f, 0.f};
    int jmax = end - 1;
    for (int j0 = beg; j0 < end; j0 += 4) {
        int src[4];
#pragma unroll
        for (int i = 0; i < 4; i++) {
            int j = j0 + i;
            src[i] = __builtin_nontemporal_load(&srcb_e[j <= jmax ? j : jmax]);
        }
        uivec4 kr[4], vr[4];
#pragma unroll
        for (int i = 0; i < 4; i++) {
            size_t so = (size_t)src[i] * 256 + c0;
            kr[i] = *(const uivec4*)&kvb[so];
            vr[i] = *(const uivec4*)&kvb[so + 128];
        }
#pragma unroll
        for (int i = 0; i < 4; i++) {
            float p = dot8_f16((const unsigned*)&kr[i], q, 0.f);
            p += __shfl_xor(p, 1, 64);  // reduce 4 lanes = 32 chans = one head
            p += __shfl_xor(p, 2, 64);
            float es = (j0 + i <= jmax) ? exp2f(p * scale) : 0.f;
            lsum += es;
            const unsigned* vu = (const unsigned*)&vr[i];
#pragma unroll
            for (int k = 0; k < 4; k++) {
                f16x2 vh; __builtin_memcpy(&vh, &vu[k], 4);
                acc[k * 2]     += es * (float)vh.x;
                acc[k * 2 + 1] += es * (float)vh.y;
            }
        }
    }
    float inv = 1.0f / (lsum + 1e-16f);
    unsigned short o[8];
#pragma unroll
    for (int i = 0; i < 8; i++) o[i] = f2bits(acc[i] * inv);
    *(bf16x8*)&aggb[rowo] = *(bf16x8*)o;   // all 64 lanes: 4 rows x 256B coalesced
}

// ---- fused outproj(l) + kqv(l+1): h' = beta*(gelu(agg)Wa+ba)+(1-beta)*h -----
// h' tile bounced through Wl rows 0..63 (hT aliases Wl, same as lin_kqv).
// aggb aliases qq: each block reads its own aggb rows before its kqv pass
// rewrites the same rows (block-private rows, barrier-ordered).
__global__ void __launch_bounds__(256, 4) outproj_kqv_gemm(const unsigned short* __restrict__ aggb,
                                                           const unsigned short* __restrict__ wTall,
                                                           const float* __restrict__ biasall,
                                                           const float* __restrict__ skipf, int l,
                                                           float* __restrict__ h,
                                                           unsigned short* __restrict__ kv,
                                                           unsigned short* __restrict__ qq) {
    __shared__ unsigned short Wl[128 * WPITCH];   // 34816 B -> 4 blocks/CU
    int bid = blockIdx.x, tid = threadIdx.x;
    int t = bid / MBLK64, nb = (bid % MBLK64) * 64;
    int lt = l * 2 + t;
    int wave = tid >> 6, lane = tid & 63;
    int m16 = lane & 15, quad = lane >> 4;
    int mat = 14 + lt;
    stage_w(Wl, wTall + (size_t)mat * 16384, tid);
    int arow = nb + wave * 16 + m16;
    int arc = arow < NN ? arow : NN - 1;
    size_t abase = ((size_t)t * NN + arc) * 128;
    bf16x8 af[4];
#pragma unroll
    for (int ks = 0; ks < 4; ks++) {
        bf16x8 raw = *(const bf16x8*)&aggb[abase + ks * 32 + quad * 8];
        const unsigned short* ru = (const unsigned short*)&raw;
        unsigned short* pu = (unsigned short*)&af[ks];
#pragma unroll
        for (int jj = 0; jj < 8; jj++) {
            float g = bits2f(ru[jj]);
            pu[jj] = f2bits(0.5f * g * (1.0f + erff(g * 0.70710678118654752f)));  // exact gelu
        }
    }
    __syncthreads();
    f32x4 acc[8];
    mfma_pass(Wl, af, biasall + mat * 128, acc, m16, quad);
    float beta = sigm(skipf[lt]);
    __syncthreads();   // all waves done reading Wl B-frags -> safe to overwrite as hT
#pragma unroll
    for (int r = 0; r < 4; r++) {
        int rloc = wave * 16 + quad * 4 + r;
        int node = nb + rloc;
#pragma unroll
        for (int ni = 0; ni < 8; ni++) {
            unsigned short vb = 0;
            if (node < NN) {
                size_t io = ((size_t)t * NN + node) * 128 + ni * 16 + m16;
                float nv = beta * acc[ni][r] + (1.0f - beta) * h[io];
                h[io] = nv;
                vb = f2bits(nv);
            }
            Wl[rloc * WPITCH + ni * 16 + m16] = vb;   // hT aliases Wl rows 0..63
        }
    }
    __syncthreads();   // hT published
    kqv_passes(Wl, Wl, wTall, biasall, /*lt=*/(l + 1) * 2 + t, kv, qq, t, nb, wave, m16, quad, tid);
}

// ---- plain outproj for the last layer: writes the final output --------------
// h store is DEAD at the last layer (h never read again) -> skipped.
__global__ void __launch_bounds__(256, 4) outproj_gemm(const unsigned short* __restrict__ aggb,
                                                       const unsigned short* __restrict__ wTall,
                                                       const float* __restrict__ biasall,
                                                       const float* __restrict__ skipf, int l,
                                                       float* __restrict__ h, int last,
                                                       void* __restrict__ outp,
                                                       const int* __restrict__ flag) {
    __shared__ unsigned short Wl[128 * WPITCH];
    int bid = blockIdx.x, tid = threadIdx.x;
    int t = bid / MBLK64, nb = (bid % MBLK64) * 64;
    int lt = l * 2 + t;
    int wave = tid >> 6, lane = tid & 63;
    int m16 = lane & 15, quad = lane >> 4;
    int mat = 14 + lt;
    stage_w(Wl, wTall + (size_t)mat * 16384, tid);
    int arow = nb + wave * 16 + m16;
    int arc = arow < NN ? arow : NN - 1;
    size_t abase = ((size_t)t * NN + arc) * 128;
    bf16x8 af[4];
#pragma unroll
    for (int ks = 0; ks < 4; ks++) {
        bf16x8 raw = *(const bf16x8*)&aggb[abase + ks * 32 + quad * 8];
        const unsigned short* ru = (const unsigned short*)&raw;
        unsigned short* pu = (unsigned short*)&af[ks];
#pragma unroll
        for (int jj = 0; jj < 8; jj++) {
            float g = bits2f(ru[jj]);
            pu[jj] = f2bits(0.5f * g * (1.0f + erff(g * 0.70710678118654752f)));  // exact gelu
        }
    }
    __syncthreads();
    f32x4 acc[8];
    mfma_pass(Wl, af, biasall + mat * 128, acc, m16, quad);
    float beta = sigm(skipf[lt]);
    int fl = *flag;
#pragma unroll
    for (int r = 0; r < 4; r++) {
        int node = nb + wave * 16 + quad * 4 + r;
        if (node < NN) {
            size_t ro = ((size_t)t * NN + node) * 128;
#pragma unroll
            for (int ni = 0; ni < 8; ni++) {
                size_t io = ro + ni * 16 + m16;
                float nv = beta * acc[ni][r] + (1.0f - beta) * h[io];
                if (!last) h[io] = nv;
                if (last) {
                    if (fl) ((float*)outp)[io] = nv;
                    else    ((bf16*)outp)[io] = __float2bfloat16(nv);
                }
            }
        }
    }
}

extern "C" void kernel_launch(void* const* d_in, const int* in_sizes, int n_in,
                              void* d_out, int out_size, void* d_ws, size_t ws_size,
                              hipStream_t stream) {
    const void* x      = d_in[0];
    const int*  ei     = (const int*)d_in[1];
    const void* ew     = d_in[2];
    const void* lin_w  = d_in[3];
    const void* lin_b  = d_in[4];
    const void* k_w    = d_in[5];
    const void* k_b    = d_in[6];
    const void* q_w    = d_in[7];
    const void* q_b    = d_in[8];
    const void* v_w    = d_in[9];
    const void* v_b    = d_in[10];
    const void* a_w    = d_in[11];
    const void* a_b    = d_in[12];
    const void* skip   = d_in[13];
    const void* rel_att = d_in[14];
    const void* rel_msg = d_in[15];
    const void* rel_p  = d_in[16];

    char* p = (char*)d_ws;
    auto alloc = [&](size_t bytes) -> char* {
        char* r = p;
        p += (bytes + 255) & ~(size_t)255;
        return r;
    };
    int* flag     = (int*)alloc(sizeof(int));
    int* gcd      = (int*)alloc(sizeof(int) * NE * CB);
    int* gcs      = (int*)alloc(sizeof(int) * NE * CB);
    int* offs     = (int*)alloc(sizeof(int) * NE * (NN + 1));
    int* srcb     = (int*)alloc(sizeof(int) * NE * NEDGE);
    unsigned* bufd = (unsigned*)alloc(sizeof(unsigned) * NE * CB * CAP);   // 6.4 MB
    unsigned* bufs = (unsigned*)alloc(sizeof(unsigned) * NE * CB * CAP);   // 6.4 MB
    unsigned short* wTall = (unsigned short*)alloc(sizeof(short) * 18 * 16384);
    float* biasall = (float*)alloc(sizeof(float) * 18 * 128);
    float* relpf   = (float*)alloc(sizeof(float) * 16);
    float* skipf   = (float*)alloc(sizeof(float) * 4);
    float* ewsc    = (float*)alloc(sizeof(float) * NT * NN);
    float* h       = (float*)alloc(sizeof(float) * NT * NN * HID);               // 51.2 MB fp32
    unsigned short* qq = (unsigned short*)alloc(sizeof(short) * NT * NN * HID);  // fp16 (aggb aliases)
    unsigned short* kv = (unsigned short*)alloc(sizeof(short) * NT * NN * HID * 2); // fp16 [K|V] interleaved
    unsigned short* aggb = qq;

    detect_kernel<<<1, 64, 0, stream>>>(x, flag, gcd, gcs);
    bucket1_kernel<<<NE * NCH, 256, 0, stream>>>(ei, gcd, gcs, bufd, bufs);
    fine_kernel<<<2 * NE * CB, 256, 0, stream>>>(bufd, bufs, gcd, gcs, ew, offs, srcb,
                                                 ewsc, flag);
    prep_w_kernel<<<18 * 64 + 18, 256, 0, stream>>>(lin_w, k_w, q_w, v_w, a_w,
                                                    lin_b, k_b, q_b, v_b, a_b,
                                                    rel_att, rel_msg, rel_p, skip,
                                                    wTall, biasall, relpf, skipf, flag);

    // fused pipeline: lin+kqv(0) -> agg(0) -> outproj(0)+kqv(1) -> agg(1) -> outproj(1,last)
    lin_kqv_gemm<<<NT * MBLK64, 256, 0, stream>>>(x, wTall, biasall, ewsc, h, kv, qq, flag);
    agg_kernel<<<NE * AGGB, 256, 0, stream>>>(qq, kv, srcb, offs, relpf, 0, aggb);
    outproj_kqv_gemm<<<NT * MBLK64, 256, 0, stream>>>(aggb, wTall, biasall, skipf, 0, h, kv, qq);
    agg_kernel<<<NE * AGGB, 256, 0, stream>>>(qq, kv, srcb, offs, relpf, 1, aggb);
    outproj_gemm<<<NT * MBLK64, 256, 0, stream>>>(aggb, wTall, biasall, skipf, 1, h, 1,
                                                  d_out, flag);
}

// Round 14
// 403.880 us; speedup vs baseline: 1.1075x; 1.0174x over previous
//
#include <hip/hip_runtime.h>
#include <hip/hip_bf16.h>
#include <math.h>

typedef __hip_bfloat16 bf16;
typedef _Float16 f16;
typedef __attribute__((ext_vector_type(2))) _Float16 f16x2;
typedef __attribute__((ext_vector_type(8))) short bf16x8;   // MFMA A/B frag (4 VGPRs)
typedef __attribute__((ext_vector_type(4))) float f32x4;    // MFMA C/D frag
typedef __attribute__((ext_vector_type(4))) unsigned uivec4; // native u32x4 (nontemporal-ok)

#define NT 2
#define NE 2
#define NN 50000
#define HID 128
#define NH 4
#define DD 32
#define NL 2
#define NEDGE 400000
#define MBLK64 782      // ceil(50000/64)
#define AGGB 3125       // NN/16 (16 dsts per block: 4 waves x 4 streams, 1 dst/stream)
#define WPITCH 136      // LDS row pitch (elems): 272 B, 16B-aligned, bank-uniform b128
#define CB 196          // coarse buckets (key >> 8), covers 50176 nodes
#define CAP 4096        // bucket capacity (expected 2040, +45 sigma margin)
#define CHUNK 2048      // edges per bucket1 block
#define NCH 196         // ceil(NEDGE / CHUNK)
#define NBUCK (NE * NCH)            // 392 bucket-role blocks
#define NPREPW (18 * 64)            // 1152 weight-prep blocks
#define NPREP (NPREPW + 18)         // + 18 misc-prep blocks

__device__ __forceinline__ float b2f(bf16 v) { return __bfloat162float(v); }
__device__ __forceinline__ float toF(float v) { return v; }
__device__ __forceinline__ float toF(bf16 v) { return b2f(v); }
__device__ __forceinline__ float sigm(float x) { return 1.0f / (1.0f + __expf(-x)); }
__device__ __forceinline__ unsigned short f2bits(float f) {
    bf16 h = __float2bfloat16(f);
    unsigned short b; __builtin_memcpy(&b, &h, 2); return b;
}
__device__ __forceinline__ float bits2f(unsigned short b) {
    unsigned u = ((unsigned)b) << 16; float f; __builtin_memcpy(&f, &u, 4); return f;
}
__device__ __forceinline__ unsigned short f2hbits(float f) {
    f16 h = (f16)f;
    unsigned short b; __builtin_memcpy(&b, &h, 2); return b;
}

__device__ __forceinline__ float dot8_f16(const unsigned* kr, const f16x2 q[4], float init) {
    float p = init;
#pragma unroll
    for (int i = 0; i < 4; i++) {
        f16x2 kh; __builtin_memcpy(&kh, &kr[i], 4);
#if __has_builtin(__builtin_amdgcn_fdot2)
        p = __builtin_amdgcn_fdot2(q[i], kh, p, false);
#else
        p += (float)q[i].x * (float)kh.x + (float)q[i].y * (float)kh.y;
#endif
    }
    return p;
}

// ---- input dtype detection (0 = bf16, 1 = fp32) + gcd/gcs zeroing -----------
__global__ void detect_kernel(const void* __restrict__ x, int* __restrict__ flag,
                              int* __restrict__ gcd, int* __restrict__ gcs) {
    int lane = threadIdx.x;  // 64
    for (int i = lane; i < NE * CB; i += 64) { gcd[i] = 0; gcs[i] = 0; }
    const unsigned short* u = (const unsigned short*)x;
    int cnt = 0;
    for (int i = 0; i < 4; i++) {
        unsigned short w = u[lane * 4 + i];
        int e = (w >> 7) & 0xFF;
        if (e >= 110 && e <= 135) cnt++;
    }
    for (int off = 32; off > 0; off >>= 1) cnt += __shfl_xor(cnt, off, 64);
    if (lane == 0) *flag = (cnt > 200) ? 0 : 1;
}

// ---- weight/bias prep bodies (role inside merged bucket_prep kernel) --------
// wT layout (bf16, [n][k]): mat 0,1 = linT; mat 2+lt*3+{0,1,2} = kT_fold,qT,vT_fold
// (lt = l*2+t); mat 14+lt = aT.
template <typename T>
__device__ __forceinline__ void prep_w_body(const T* lin_w, const T* k_w, const T* q_w,
                                            const T* v_w, const T* a_w, const T* rel_att,
                                            const T* rel_msg, unsigned short* wT, int pbid) {
    int tid = threadIdx.x;
    int mat = pbid >> 6;
    int elem = (pbid & 63) * 256 + tid;
    int n = elem >> 7, k = elem & 127;
    float v;
    if (mat < 2) {
        v = toF(lin_w[(size_t)mat * 16384 + k * 128 + n]);
    } else if (mat < 14) {
        int m2 = mat - 2, lt = m2 / 3, op = m2 % 3;
        if (op == 1) {
            v = toF(q_w[(size_t)lt * 16384 + k * 128 + n]);
        } else {
            const T* w = (op == 0 ? k_w : v_w) + (size_t)lt * 16384 + k * 128;
            const T* rl = (op == 0 ? rel_att : rel_msg) + (size_t)lt * 4096;  // e == t
            int hh = n >> 5, jj = n & 31;
            float s = 0.f;
#pragma unroll 8
            for (int d = 0; d < 32; d++)
                s += toF(w[hh * 32 + d]) * toF(rl[(hh * 32 + d) * 32 + jj]);
            v = s;
        }
    } else {
        v = toF(a_w[(size_t)(mat - 14) * 16384 + k * 128 + n]);
    }
    wT[(size_t)mat * 16384 + n * 128 + k] = f2bits(v);
}
template <typename T>
__device__ __forceinline__ void prep_misc_body(const T* lin_b, const T* k_b, const T* q_b,
                                               const T* v_b, const T* a_b, const T* rel_att,
                                               const T* rel_msg, const T* rel_p, const T* skip,
                                               float* biasall, float* relpf, float* skipf,
                                               int mat, int n) {
    float v;
    if (mat < 2) {
        v = toF(lin_b[mat * 128 + n]);
    } else if (mat < 14) {
        int m2 = mat - 2, lt = m2 / 3, op = m2 % 3;
        if (op == 1) {
            v = toF(q_b[lt * 128 + n]);
        } else {
            const T* b = (op == 0 ? k_b : v_b) + lt * 128;
            const T* rl = (op == 0 ? rel_att : rel_msg) + (size_t)lt * 4096;
            int hh = n >> 5, jj = n & 31;
            float s = 0.f;
#pragma unroll 8
            for (int d = 0; d < 32; d++)
                s += toF(b[hh * 32 + d]) * toF(rl[(hh * 32 + d) * 32 + jj]);
            v = s;
        }
    } else {
        v = toF(a_b[(mat - 14) * 128 + n]);
    }
    biasall[mat * 128 + n] = v;
    if (mat == 0 && n < 16) relpf[n] = toF(rel_p[n]);
    if (mat == 1 && n < 4) skipf[n] = toF(skip[n]);
}

// ---- merged coarse-bucketing + weight-prep (independent roles; round-13) ----
// bid < NBUCK: one edge-pass bucketing chunk (dst-keyed + src-keyed).
//   bufd record: (dst&255)<<24 | src.  bufs record: (src&255)<<19 | j.
// bid >= NBUCK: weight-prep (transpose + rel-fold) / bias-prep blocks.
// Both roles depend only on detect_kernel; merging removes a launch boundary
// and overlaps prep work with the bucketing memory phase.
__global__ void bucket_prep_kernel(const int* __restrict__ ei, int* __restrict__ gcd,
                                   int* __restrict__ gcs, unsigned* __restrict__ bufd,
                                   unsigned* __restrict__ bufs,
                                   const void* lin_w, const void* k_w, const void* q_w,
                                   const void* v_w, const void* a_w,
                                   const void* lin_b, const void* k_b, const void* q_b,
                                   const void* v_b, const void* a_b,
                                   const void* rel_att, const void* rel_msg,
                                   const void* rel_p, const void* skip,
                                   unsigned short* wT, float* biasall, float* relpf,
                                   float* skipf, const int* flag) {
    int bid = blockIdx.x;               // NBUCK + NPREP
    int tid = threadIdx.x;              // 256
    if (bid >= NBUCK) {
        int pbid = bid - NBUCK;
        if (pbid < NPREPW) {
            if (*flag) prep_w_body<float>((const float*)lin_w, (const float*)k_w,
                                          (const float*)q_w, (const float*)v_w,
                                          (const float*)a_w, (const float*)rel_att,
                                          (const float*)rel_msg, wT, pbid);
            else       prep_w_body<bf16>((const bf16*)lin_w, (const bf16*)k_w,
                                         (const bf16*)q_w, (const bf16*)v_w,
                                         (const bf16*)a_w, (const bf16*)rel_att,
                                         (const bf16*)rel_msg, wT, pbid);
        } else {
            int mat = pbid - NPREPW, n = tid;
            if (n < 128) {
                if (*flag) prep_misc_body<float>((const float*)lin_b, (const float*)k_b,
                                                 (const float*)q_b, (const float*)v_b,
                                                 (const float*)a_b, (const float*)rel_att,
                                                 (const float*)rel_msg, (const float*)rel_p,
                                                 (const float*)skip, biasall, relpf, skipf,
                                                 mat, n);
                else       prep_misc_body<bf16>((const bf16*)lin_b, (const bf16*)k_b,
                                                (const bf16*)q_b, (const bf16*)v_b,
                                                (const bf16*)a_b, (const bf16*)rel_att,
                                                (const bf16*)rel_msg, (const bf16*)rel_p,
                                                (const bf16*)skip, biasall, relpf, skipf,
                                                mat, n);
            }
        }
        return;
    }
    int e = bid / NCH, ch = bid % NCH;
    __shared__ int hd[CB], hs[CB], bd[CB], bs[CB];
    for (int i = tid; i < CB; i += 256) { hd[i] = 0; hs[i] = 0; }
    __syncthreads();
    const int* srcp = ei + (e * 2 + 0) * NEDGE;
    const int* dstp = ei + (e * 2 + 1) * NEDGE;
    int j0 = ch * CHUNK;
    int src[8], dst[8], rd[8], rs[8];
#pragma unroll
    for (int i = 0; i < 8; i++) {
        int j = j0 + i * 256 + tid;
        if (j < NEDGE) {
            src[i] = srcp[j]; dst[i] = dstp[j];
            rd[i] = atomicAdd(&hd[dst[i] >> 8], 1);
            rs[i] = atomicAdd(&hs[src[i] >> 8], 1);
        } else src[i] = -1;
    }
    __syncthreads();
    for (int i = tid; i < CB; i += 256) {
        bd[i] = hd[i] ? atomicAdd(&gcd[e * CB + i], hd[i]) : 0;
        bs[i] = hs[i] ? atomicAdd(&gcs[e * CB + i], hs[i]) : 0;
    }
    __syncthreads();
#pragma unroll
    for (int i = 0; i < 8; i++) {
        int j = j0 + i * 256 + tid;
        if (j < NEDGE) {
            int bn = dst[i] >> 8;
            int pd = bd[bn] + rd[i]; if (pd >= CAP) pd = CAP - 1;   // defensive
            bufd[((size_t)e * CB + bn) * CAP + pd] =
                ((unsigned)(dst[i] & 255) << 24) | (unsigned)src[i];
            bn = src[i] >> 8;
            int ps = bs[bn] + rs[i]; if (ps >= CAP) ps = CAP - 1;   // defensive
            bufs[((size_t)e * CB + bn) * CAP + ps] =
                ((unsigned)(src[i] & 255) << 19) | (unsigned)j;
        }
    }
}

// ---- combined fine pass (launch-merged; round-12) ---------------------------
// blk < NE*CB: dst role -- per-bucket exact CSR offs + dst-sorted srcb. The
//   coarse base is recomputed per block as a 196-element LDS tree-sum over gcd.
// blk >= NE*CB: src role -- per-src last-edge-index max -> ewsc.
__global__ void fine_kernel(const unsigned* __restrict__ bufd,
                            const unsigned* __restrict__ bufs,
                            const int* __restrict__ gcd, const int* __restrict__ gcs,
                            const void* __restrict__ ew, int* __restrict__ offs,
                            int* __restrict__ srcb, float* __restrict__ ewsc,
                            const int* __restrict__ flag) {
    int blk = blockIdx.x;               // 2 * NE * CB
    int tid = threadIdx.x;              // 256
    __shared__ int dc[256], ss[256];
    if (blk < NE * CB) {
        // ---------------- dst role ----------------
        int e = blk / CB, bn = blk % CB;
        int cntr = gcd[e * CB + bn];
        int cnt = cntr > CAP ? CAP : cntr;
        // base = sum of gcd[e*CB + i] for i < bn (exclusive coarse prefix)
        ss[tid] = (tid < bn) ? gcd[e * CB + tid] : 0;
        __syncthreads();
        for (int off = 128; off > 0; off >>= 1) {
            if (tid < off) ss[tid] += ss[tid + off];
            __syncthreads();
        }
        int base = ss[0];
        __syncthreads();
        if (tid == 0 && bn == 0) offs[e * (NN + 1) + NN] = NEDGE;   // sentinel
        const unsigned* b = bufd + ((size_t)e * CB + bn) * CAP;
        dc[tid] = 0; __syncthreads();
        for (int i = tid; i < cnt; i += 256) atomicAdd(&dc[b[i] >> 24], 1);
        __syncthreads();
        int v = dc[tid];
        ss[tid] = v; __syncthreads();
        for (int off = 1; off < 256; off <<= 1) {
            int a = (tid >= off) ? ss[tid - off] : 0;
            __syncthreads();
            ss[tid] += a;
            __syncthreads();
        }
        int excl = ss[tid] - v;
        int d = bn * 256 + tid;
        if (d < NN) offs[e * (NN + 1) + d] = base + excl;
        dc[tid] = excl;                 // reuse as scatter cursor
        __syncthreads();
        for (int i = tid; i < cnt; i += 256) {
            unsigned w = b[i];
            int r = atomicAdd(&dc[w >> 24], 1);
            srcb[(size_t)e * NEDGE + base + r] = (int)(w & 0xFFFFFF);
        }
    } else {
        // ---------------- src role ----------------
        int blk2 = blk - NE * CB;
        int e = blk2 / CB, bn = blk2 % CB;
        int cnt = gcs[e * CB + bn]; if (cnt > CAP) cnt = CAP;
        const unsigned* b = bufs + ((size_t)e * CB + bn) * CAP;
        dc[tid] = -1; __syncthreads();
        for (int i = tid; i < cnt; i += 256) {
            unsigned w = b[i];
            atomicMax(&dc[w >> 19], (int)(w & 0x7FFFF));
        }
        __syncthreads();
        int n = bn * 256 + tid;
        if (n < NN) {
            int mj = dc[tid];
            float v = 1.0f;
            if (mj >= 0)
                v = sigm(*flag ? ((const float*)ew)[(size_t)e * NEDGE + mj]
                               : b2f(((const bf16*)ew)[(size_t)e * NEDGE + mj]));
            ewsc[e * NN + n] = v;       // src type of edge type e == e
        }
    }
}

// ---- shared GEMM helpers ----------------------------------------------------
__device__ __forceinline__ void stage_w(unsigned short* __restrict__ Wl,
                                        const unsigned short* __restrict__ wmat, int tid) {
#pragma unroll
    for (int i = 0; i < 8; i++) {
        int c = i * 256 + tid;           // 2048 chunks of 8
        int n = c >> 4, ko = (c & 15) * 8;
        *(bf16x8*)&Wl[n * WPITCH + ko] = *(const bf16x8*)&wmat[n * 128 + ko];
    }
}

__device__ __forceinline__ void mfma_pass(const unsigned short* __restrict__ Wl,
                                          const bf16x8 af[4], const float* __restrict__ bias,
                                          f32x4 acc[8], int m16, int quad) {
#pragma unroll
    for (int ni = 0; ni < 8; ni++) {
        float b = bias[ni * 16 + m16];
        f32x4 iv = {b, b, b, b};
        acc[ni] = iv;
    }
#pragma unroll
    for (int ks = 0; ks < 4; ks++) {
        bf16x8 a = af[ks];
#pragma unroll
        for (int ni = 0; ni < 8; ni++) {
            bf16x8 bb = *(const bf16x8*)&Wl[(ni * 16 + m16) * WPITCH + ks * 32 + quad * 8];
            acc[ni] = __builtin_amdgcn_mfma_f32_16x16x32_bf16(a, bb, acc[ni], 0, 0, 0);
        }
    }
}

// kqv 3-pass GEMM on an LDS-staged A tile. hT may ALIAS Wl (rows 0..63): the
// af2 registers are loaded from hT before pass 0's barrier+restage overwrites
// Wl, and the pass-0 barrier (lgkmcnt-draining) orders those reads. Writes
// K/V interleaved + q with scalar 2B stores (L2 write-combines them; the
// vectorized LDS-bounce variant measured slower -- round-9 lesson).
__device__ __forceinline__ void kqv_passes(const unsigned short* __restrict__ hT,
                                           unsigned short* __restrict__ Wl,
                                           const unsigned short* __restrict__ wTall,
                                           const float* __restrict__ biasall, int lt,
                                           unsigned short* __restrict__ kv,
                                           unsigned short* __restrict__ qq,
                                           int t, int nb, int wave, int m16, int quad, int tid) {
    bf16x8 af2[4];
#pragma unroll
    for (int ks = 0; ks < 4; ks++)
        af2[ks] = *(const bf16x8*)&hT[(wave * 16 + m16) * WPITCH + ks * 32 + quad * 8];
    f32x4 acc[8];
#pragma unroll
    for (int pass = 0; pass < 3; pass++) {
        int mat = 2 + lt * 3 + pass;
        __syncthreads();   // prior reads of Wl/hT (incl. af2 loads) done before restage
        stage_w(Wl, wTall + (size_t)mat * 16384, tid);
        __syncthreads();
        mfma_pass(Wl, af2, biasall + mat * 128, acc, m16, quad);
#pragma unroll
        for (int r = 0; r < 4; r++) {
            int node = nb + wave * 16 + quad * 4 + r;
            if (node < NN) {
#pragma unroll
                for (int ni = 0; ni < 8; ni++) {
                    unsigned short hb = f2hbits(acc[ni][r]);
                    int c = ni * 16 + m16;
                    if (pass == 1) {
                        qq[((size_t)t * NN + node) * 128 + c] = hb;
                    } else {
                        size_t ro = ((size_t)t * NN + node) * 256 + (pass == 0 ? 0 : 128);
                        kv[ro + c] = hb;
                    }
                }
            }
        }
    }
}

// ---- fused lin + kqv(l=0): x -> h = relu(xW+b)*ewsc -> {K|V}, q -------------
// The transposed h tile is bounced through Wl's FIRST 64 ROWS (hT aliases Wl):
// after mfma_pass a barrier retires all waves' W-fragment reads, the tile is
// written, another barrier publishes it, af2 is read, and pass 0 restages Wl.
// LDS = Wl only (34816 B) -> 4 blocks/CU.
template <bool FP32>
__device__ __forceinline__ void lin_kqv_body(const void* __restrict__ x,
                                             const unsigned short* __restrict__ wTall,
                                             const float* __restrict__ biasall,
                                             const float* __restrict__ ewsc,
                                             float* __restrict__ h,
                                             unsigned short* __restrict__ kv,
                                             unsigned short* __restrict__ qq,
                                             unsigned short* __restrict__ Wl) {
    int bid = blockIdx.x, tid = threadIdx.x;
    int t = bid / MBLK64, nb = (bid % MBLK64) * 64;
    int wave = tid >> 6, lane = tid & 63;
    int m16 = lane & 15, quad = lane >> 4;
    stage_w(Wl, wTall + (size_t)t * 16384, tid);
    int arow = nb + wave * 16 + m16;
    int arc = arow < NN ? arow : NN - 1;
    size_t abase = ((size_t)t * NN + arc) * 128;
    bf16x8 af[4];
#pragma unroll
    for (int ks = 0; ks < 4; ks++) {
        if (FP32) {
            const float4* s = (const float4*)((const float*)x + abase + ks * 32 + quad * 8);
            float4 f0 = s[0], f1 = s[1];
            unsigned short* pu = (unsigned short*)&af[ks];
            pu[0] = f2bits(f0.x); pu[1] = f2bits(f0.y); pu[2] = f2bits(f0.z); pu[3] = f2bits(f0.w);
            pu[4] = f2bits(f1.x); pu[5] = f2bits(f1.y); pu[6] = f2bits(f1.z); pu[7] = f2bits(f1.w);
        } else {
            af[ks] = *(const bf16x8*)((const unsigned short*)x + abase + ks * 32 + quad * 8);
        }
    }
    __syncthreads();
    f32x4 acc[8];
    mfma_pass(Wl, af, biasall + t * 128, acc, m16, quad);
    __syncthreads();   // all waves done reading Wl B-frags -> safe to overwrite as hT
#pragma unroll
    for (int r = 0; r < 4; r++) {
        int rloc = wave * 16 + quad * 4 + r;
        int node = nb + rloc;
        float es = ewsc[t * NN + (node < NN ? node : NN - 1)];
#pragma unroll
        for (int ni = 0; ni < 8; ni++) {
            float v = fmaxf(acc[ni][r], 0.f) * es;
            unsigned short vb = (node < NN) ? f2bits(v) : (unsigned short)0;
            if (node < NN) h[((size_t)t * NN + node) * 128 + ni * 16 + m16] = v;
            Wl[rloc * WPITCH + ni * 16 + m16] = vb;   // hT aliases Wl rows 0..63
        }
    }
    __syncthreads();   // hT published
    kqv_passes(Wl, Wl, wTall, biasall, /*lt=*/t, kv, qq, t, nb, wave, m16, quad, tid);
}
__global__ void __launch_bounds__(256, 4) lin_kqv_gemm(const void* x,
                                                       const unsigned short* wTall,
                                                       const float* biasall, const float* ewsc,
                                                       float* h, unsigned short* kv,
                                                       unsigned short* qq, const int* flag) {
    __shared__ unsigned short Wl[128 * WPITCH];   // 34816 B -> 4 blocks/CU
    if (*flag) lin_kqv_body<true>(x, wTall, biasall, ewsc, h, kv, qq, Wl);
    else       lin_kqv_body<false>(x, wTall, biasall, ewsc, h, kv, qq, Wl);
}

// ---- merged-edge-type segment-softmax aggregation (r4-proven, at line-traffic
// roofline: 512 B/edge * 800k = 410 MB L2-line traffic @ ~6.6 TB/s = ~62 us) ---
__global__ void __launch_bounds__(256) agg_kernel(const unsigned short* __restrict__ qq,
                                                  const unsigned short* __restrict__ kv,
                                                  const int* __restrict__ srcb,
                                                  const int* __restrict__ offs,
                                                  const float* __restrict__ relpf, int l,
                                                  unsigned short* __restrict__ aggb) {
    int bid = blockIdx.x;
    int e = bid / AGGB;
    int wave = threadIdx.x >> 6, lane = threadIdx.x & 63;
    int stream = lane >> 4, l4 = lane & 15;
    int dst = (bid % AGGB) * 16 + wave * 4 + stream;
    int t = 1 - e;                      // EDGE_DST=(1,0)
    int le = l * 2 + e;
    int c0 = l4 * 8, head = l4 >> 2;
    const int* offs_e = offs + e * (NN + 1);
    const int* srcb_e = srcb + (size_t)e * NEDGE;
    int beg = offs_e[dst], end = offs_e[dst + 1];
    size_t rowo = ((size_t)t * NN + dst) * 128 + c0;
    float scale = relpf[le * 4 + head] * 0.17677669529663687f * 1.44269504088896f;
    uivec4 qraw = __builtin_nontemporal_load((const uivec4*)&qq[rowo]);
    f16x2 q[4];
#pragma unroll
    for (int i = 0; i < 4; i++) { unsigned w = qraw[i]; __builtin_memcpy(&q[i], &w, 4); }
    const unsigned short* kvb = kv + (size_t)e * NN * 256;  // EDGE_SRC=(0,1): s == e
    float lsum = 0.f;
    float acc[8] = {0.f, 0.f, 0.f, 0.f, 0.f, 0.f, 0.f, 0.f};
    int jmax = end - 1;
    for (int j0 = beg; j0 < end; j0 += 4) {
        int src[4];
#pragma unroll
        for (int i = 0; i < 4; i++) {
            int j = j0 + i;
            src[i] = __builtin_nontemporal_load(&srcb_e[j <= jmax ? j : jmax]);
        }
        uivec4 kr[4], vr[4];
#pragma unroll
        for (int i = 0; i < 4; i++) {
            size_t so = (size_t)src[i] * 256 + c0;
            kr[i] = *(const uivec4*)&kvb[so];
            vr[i] = *(const uivec4*)&kvb[so + 128];
        }
#pragma unroll
        for (int i = 0; i < 4; i++) {
            float p = dot8_f16((const unsigned*)&kr[i], q, 0.f);
            p += __shfl_xor(p, 1, 64);  // reduce 4 lanes = 32 chans = one head
            p += __shfl_xor(p, 2, 64);
            float es = (j0 + i <= jmax) ? exp2f(p * scale) : 0.f;
            lsum += es;
            const unsigned* vu = (const unsigned*)&vr[i];
#pragma unroll
            for (int k = 0; k < 4; k++) {
                f16x2 vh; __builtin_memcpy(&vh, &vu[k], 4);
                acc[k * 2]     += es * (float)vh.x;
                acc[k * 2 + 1] += es * (float)vh.y;
            }
        }
    }
    float inv = 1.0f / (lsum + 1e-16f);
    unsigned short o[8];
#pragma unroll
    for (int i = 0; i < 8; i++) o[i] = f2bits(acc[i] * inv);
    *(bf16x8*)&aggb[rowo] = *(bf16x8*)o;   // all 64 lanes: 4 rows x 256B coalesced
}

// ---- fused outproj(l) + kqv(l+1): h' = beta*(gelu(agg)Wa+ba)+(1-beta)*h -----
// h' tile bounced through Wl rows 0..63 (hT aliases Wl, same as lin_kqv).
// aggb aliases qq: each block reads its own aggb rows before its kqv pass
// rewrites the same rows (block-private rows, barrier-ordered).
__global__ void __launch_bounds__(256, 4) outproj_kqv_gemm(const unsigned short* __restrict__ aggb,
                                                           const unsigned short* __restrict__ wTall,
                                                           const float* __restrict__ biasall,
                                                           const float* __restrict__ skipf, int l,
                                                           float* __restrict__ h,
                                                           unsigned short* __restrict__ kv,
                                                           unsigned short* __restrict__ qq) {
    __shared__ unsigned short Wl[128 * WPITCH];   // 34816 B -> 4 blocks/CU
    int bid = blockIdx.x, tid = threadIdx.x;
    int t = bid / MBLK64, nb = (bid % MBLK64) * 64;
    int lt = l * 2 + t;
    int wave = tid >> 6, lane = tid & 63;
    int m16 = lane & 15, quad = lane >> 4;
    int mat = 14 + lt;
    stage_w(Wl, wTall + (size_t)mat * 16384, tid);
    int arow = nb + wave * 16 + m16;
    int arc = arow < NN ? arow : NN - 1;
    size_t abase = ((size_t)t * NN + arc) * 128;
    bf16x8 af[4];
#pragma unroll
    for (int ks = 0; ks < 4; ks++) {
        bf16x8 raw = *(const bf16x8*)&aggb[abase + ks * 32 + quad * 8];
        const unsigned short* ru = (const unsigned short*)&raw;
        unsigned short* pu = (unsigned short*)&af[ks];
#pragma unroll
        for (int jj = 0; jj < 8; jj++) {
            float g = bits2f(ru[jj]);
            pu[jj] = f2bits(0.5f * g * (1.0f + erff(g * 0.70710678118654752f)));  // exact gelu
        }
    }
    __syncthreads();
    f32x4 acc[8];
    mfma_pass(Wl, af, biasall + mat * 128, acc, m16, quad);
    float beta = sigm(skipf[lt]);
    __syncthreads();   // all waves done reading Wl B-frags -> safe to overwrite as hT
#pragma unroll
    for (int r = 0; r < 4; r++) {
        int rloc = wave * 16 + quad * 4 + r;
        int node = nb + rloc;
#pragma unroll
        for (int ni = 0; ni < 8; ni++) {
            unsigned short vb = 0;
            if (node < NN) {
                size_t io = ((size_t)t * NN + node) * 128 + ni * 16 + m16;
                float nv = beta * acc[ni][r] + (1.0f - beta) * h[io];
                h[io] = nv;
                vb = f2bits(nv);
            }
            Wl[rloc * WPITCH + ni * 16 + m16] = vb;   // hT aliases Wl rows 0..63
        }
    }
    __syncthreads();   // hT published
    kqv_passes(Wl, Wl, wTall, biasall, /*lt=*/(l + 1) * 2 + t, kv, qq, t, nb, wave, m16, quad, tid);
}

// ---- plain outproj for the last layer: writes the final output --------------
// h store is DEAD at the last layer (h never read again) -> skipped.
__global__ void __launch_bounds__(256, 4) outproj_gemm(const unsigned short* __restrict__ aggb,
                                                       const unsigned short* __restrict__ wTall,
                                                       const float* __restrict__ biasall,
                                                       const float* __restrict__ skipf, int l,
                                                       float* __restrict__ h, int last,
                                                       void* __restrict__ outp,
                                                       const int* __restrict__ flag) {
    __shared__ unsigned short Wl[128 * WPITCH];
    int bid = blockIdx.x, tid = threadIdx.x;
    int t = bid / MBLK64, nb = (bid % MBLK64) * 64;
    int lt = l * 2 + t;
    int wave = tid >> 6, lane = tid & 63;
    int m16 = lane & 15, quad = lane >> 4;
    int mat = 14 + lt;
    stage_w(Wl, wTall + (size_t)mat * 16384, tid);
    int arow = nb + wave * 16 + m16;
    int arc = arow < NN ? arow : NN - 1;
    size_t abase = ((size_t)t * NN + arc) * 128;
    bf16x8 af[4];
#pragma unroll
    for (int ks = 0; ks < 4; ks++) {
        bf16x8 raw = *(const bf16x8*)&aggb[abase + ks * 32 + quad * 8];
        const unsigned short* ru = (const unsigned short*)&raw;
        unsigned short* pu = (unsigned short*)&af[ks];
#pragma unroll
        for (int jj = 0; jj < 8; jj++) {
            float g = bits2f(ru[jj]);
            pu[jj] = f2bits(0.5f * g * (1.0f + erff(g * 0.70710678118654752f)));  // exact gelu
        }
    }
    __syncthreads();
    f32x4 acc[8];
    mfma_pass(Wl, af, biasall + mat * 128, acc, m16, quad);
    float beta = sigm(skipf[lt]);
    int fl = *flag;
#pragma unroll
    for (int r = 0; r < 4; r++) {
        int node = nb + wave * 16 + quad * 4 + r;
        if (node < NN) {
            size_t ro = ((size_t)t * NN + node) * 128;
#pragma unroll
            for (int ni = 0; ni < 8; ni++) {
                size_t io = ro + ni * 16 + m16;
                float nv = beta * acc[ni][r] + (1.0f - beta) * h[io];
                if (!last) h[io] = nv;
                if (last) {
                    if (fl) ((float*)outp)[io] = nv;
                    else    ((bf16*)outp)[io] = __float2bfloat16(nv);
                }
            }
        }
    }
}

extern "C" void kernel_launch(void* const* d_in, const int* in_sizes, int n_in,
                              void* d_out, int out_size, void* d_ws, size_t ws_size,
                              hipStream_t stream) {
    const void* x      = d_in[0];
    const int*  ei     = (const int*)d_in[1];
    const void* ew     = d_in[2];
    const void* lin_w  = d_in[3];
    const void* lin_b  = d_in[4];
    const void* k_w    = d_in[5];
    const void* k_b    = d_in[6];
    const void* q_w    = d_in[7];
    const void* q_b    = d_in[8];
    const void* v_w    = d_in[9];
    const void* v_b    = d_in[10];
    const void* a_w    = d_in[11];
    const void* a_b    = d_in[12];
    const void* skip   = d_in[13];
    const void* rel_att = d_in[14];
    const void* rel_msg = d_in[15];
    const void* rel_p  = d_in[16];

    char* p = (char*)d_ws;
    auto alloc = [&](size_t bytes) -> char* {
        char* r = p;
        p += (bytes + 255) & ~(size_t)255;
        return r;
    };
    int* flag     = (int*)alloc(sizeof(int));
    int* gcd      = (int*)alloc(sizeof(int) * NE * CB);
    int* gcs      = (int*)alloc(sizeof(int) * NE * CB);
    int* offs     = (int*)alloc(sizeof(int) * NE * (NN + 1));
    int* srcb     = (int*)alloc(sizeof(int) * NE * NEDGE);
    unsigned* bufd = (unsigned*)alloc(sizeof(unsigned) * NE * CB * CAP);   // 6.4 MB
    unsigned* bufs = (unsigned*)alloc(sizeof(unsigned) * NE * CB * CAP);   // 6.4 MB
    unsigned short* wTall = (unsigned short*)alloc(sizeof(short) * 18 * 16384);
    float* biasall = (float*)alloc(sizeof(float) * 18 * 128);
    float* relpf   = (float*)alloc(sizeof(float) * 16);
    float* skipf   = (float*)alloc(sizeof(float) * 4);
    float* ewsc    = (float*)alloc(sizeof(float) * NT * NN);
    float* h       = (float*)alloc(sizeof(float) * NT * NN * HID);               // 51.2 MB fp32
    unsigned short* qq = (unsigned short*)alloc(sizeof(short) * NT * NN * HID);  // fp16 (aggb aliases)
    unsigned short* kv = (unsigned short*)alloc(sizeof(short) * NT * NN * HID * 2); // fp16 [K|V] interleaved
    unsigned short* aggb = qq;

    detect_kernel<<<1, 64, 0, stream>>>(x, flag, gcd, gcs);
    bucket_prep_kernel<<<NBUCK + NPREP, 256, 0, stream>>>(ei, gcd, gcs, bufd, bufs,
                                                          lin_w, k_w, q_w, v_w, a_w,
                                                          lin_b, k_b, q_b, v_b, a_b,
                                                          rel_att, rel_msg, rel_p, skip,
                                                          wTall, biasall, relpf, skipf, flag);
    fine_kernel<<<2 * NE * CB, 256, 0, stream>>>(bufd, bufs, gcd, gcs, ew, offs, srcb,
                                                 ewsc, flag);

    // fused pipeline: lin+kqv(0) -> agg(0) -> outproj(0)+kqv(1) -> agg(1) -> outproj(1,last)
    lin_kqv_gemm<<<NT * MBLK64, 256, 0, stream>>>(x, wTall, biasall, ewsc, h, kv, qq, flag);
    agg_kernel<<<NE * AGGB, 256, 0, stream>>>(qq, kv, srcb, offs, relpf, 0, aggb);
    outproj_kqv_gemm<<<NT * MBLK64, 256, 0, stream>>>(aggb, wTall, biasall, skipf, 0, h, kv, qq);
    agg_kernel<<<NE * AGGB, 256, 0, stream>>>(qq, kv, srcb, offs, relpf, 1, aggb);
    outproj_gemm<<<NT * MBLK64, 256, 0, stream>>>(aggb, wTall, biasall, skipf, 1, h, 1,
                                                  d_out, flag);
}